// Round 3
// baseline (6211.300 us; speedup 1.0000x reference)
//
#include <hip/hip_runtime.h>
#include <math.h>

#define HIDDEN 4096
#define NH 32
#define HD 128
#define PLEN 10
#define SEQQ 2048
#define QT 32
#define KT 64

// ---------------- RoPE cos/sin tables ----------------
__global__ void rope_table_kernel(const int* __restrict__ pos,
                                  float* __restrict__ cosT, float* __restrict__ sinT)
{
    int s = blockIdx.x;
    int j = threadIdx.x;               // 0..63
    float p = (float)pos[s];
    float expnt = (2.0f * (float)j) * (1.0f / 128.0f);
    float inv_freq = powf(10000.0f, -expnt);
    float f = p * inv_freq;
    cosT[s * 64 + j] = cosf(f);
    sinT[s * 64 + j] = sinf(f);
}

// ---------------- fp32 GEMM NT: C[M,N] = A[M,K] * B[N,K]^T ----------------
// 128x128 tile, BK=8, 256 threads, 8x8 per thread.
__global__ __launch_bounds__(256) void gemm_nt_kernel(
    const float* __restrict__ A, const float* __restrict__ B, float* __restrict__ C,
    int M, int N, int K)
{
    __shared__ float As[8][132];
    __shared__ float Bs[8][132];
    const int tid = threadIdx.x;
    const int tx = tid & 15, ty = tid >> 4;
    const int m0 = blockIdx.y * 128, n0 = blockIdx.x * 128;
    const int lr = tid >> 1;            // 0..127
    const int lk = (tid & 1) * 4;       // 0 or 4
    const bool aval = (m0 + lr) < M;
    const float* Ap = A + (size_t)(m0 + lr) * K + lk;
    const float* Bp = B + (size_t)(n0 + lr) * K + lk;

    float acc[8][8];
#pragma unroll
    for (int i = 0; i < 8; ++i)
#pragma unroll
        for (int j = 0; j < 8; ++j) acc[i][j] = 0.0f;

    for (int k0 = 0; k0 < K; k0 += 8) {
        float4 a4 = make_float4(0.f, 0.f, 0.f, 0.f);
        if (aval) a4 = *(const float4*)(Ap + k0);
        float4 b4 = *(const float4*)(Bp + k0);
        __syncthreads();
        As[lk + 0][lr] = a4.x; As[lk + 1][lr] = a4.y; As[lk + 2][lr] = a4.z; As[lk + 3][lr] = a4.w;
        Bs[lk + 0][lr] = b4.x; Bs[lk + 1][lr] = b4.y; Bs[lk + 2][lr] = b4.z; Bs[lk + 3][lr] = b4.w;
        __syncthreads();
#pragma unroll
        for (int kk = 0; kk < 8; ++kk) {
            float4 a0 = *(const float4*)&As[kk][ty * 8];
            float4 a1 = *(const float4*)&As[kk][ty * 8 + 4];
            float4 b0 = *(const float4*)&Bs[kk][tx * 8];
            float4 b1 = *(const float4*)&Bs[kk][tx * 8 + 4];
            float a[8] = {a0.x, a0.y, a0.z, a0.w, a1.x, a1.y, a1.z, a1.w};
            float b[8] = {b0.x, b0.y, b0.z, b0.w, b1.x, b1.y, b1.z, b1.w};
#pragma unroll
            for (int i = 0; i < 8; ++i)
#pragma unroll
                for (int j = 0; j < 8; ++j)
                    acc[i][j] = fmaf(a[i], b[j], acc[i][j]);
        }
    }
#pragma unroll
    for (int i = 0; i < 8; ++i) {
        int row = m0 + ty * 8 + i;
        if (row < M) {
            float* Cp = C + (size_t)row * N + n0 + tx * 8;
            *(float4*)Cp       = make_float4(acc[i][0], acc[i][1], acc[i][2], acc[i][3]);
            *(float4*)(Cp + 4) = make_float4(acc[i][4], acc[i][5], acc[i][6], acc[i][7]);
        }
    }
}

// ---------------- RoPE apply in place on q and k ----------------
__global__ void rope_apply_kernel(float* __restrict__ q, float* __restrict__ k,
                                  const float* __restrict__ cosT, const float* __restrict__ sinT)
{
    int idx = blockIdx.x * 256 + threadIdx.x;   // < SEQQ * 2048
    int s = idx >> 11;
    int rem = idx & 2047;
    int h = rem >> 6;
    int d = rem & 63;
    float c = cosT[s * 64 + d], sn = sinT[s * 64 + d];
    size_t base = (size_t)s * HIDDEN + h * HD + d;
    float a = q[base], b = q[base + 64];
    q[base]      = a * c - b * sn;
    q[base + 64] = b * c + a * sn;
    a = k[base]; b = k[base + 64];
    k[base]      = a * c - b * sn;
    k[base + 64] = b * c + a * sn;
}

// ---------------- fused attention (token flash + gated prefix) ----------------
// grid (SEQQ/QT, NH), 256 threads. Writes output in place into q's region.
__global__ __launch_bounds__(256) void attn_kernel(
    const float* __restrict__ q, const float* __restrict__ k, const float* __restrict__ v,
    const float* __restrict__ kp, const float* __restrict__ vp,
    const float* __restrict__ gate, float* __restrict__ out)
{
    __shared__ float Qt[128][36];      // [d][r], padded
    __shared__ float KV[128 * 68];     // Kt[d][j] stride 68  OR  Vs[j][d] stride 136
    __shared__ float Ps[QT][68];       // scores / probs

    const int h = blockIdx.y;
    const int r0 = blockIdx.x * QT;
    const int tid = threadIdx.x;
    const int orow = tid >> 3;          // 0..31  output row
    const int oc4 = (tid & 7) * 4;      // output col base (x4, stride-32 groups)
    const int sy = tid >> 4;            // score rows sy*2..+1
    const int sx = tid & 15;            // score cols sx*4..+3
    const float scale = 0.088388347648318447f;   // 1/sqrt(128)

    // load Q tile transposed
#pragma unroll
    for (int i = 0; i < 4; ++i) {
        int flat = tid + 256 * i;       // 0..1023
        int r = flat >> 5;
        int d = (flat & 31) << 2;
        float4 t = *(const float4*)(q + (size_t)(r0 + r) * HIDDEN + h * HD + d);
        Qt[d + 0][r] = t.x; Qt[d + 1][r] = t.y; Qt[d + 2][r] = t.z; Qt[d + 3][r] = t.w;
    }

    float acc[4][4];
#pragma unroll
    for (int u = 0; u < 4; ++u)
#pragma unroll
        for (int i = 0; i < 4; ++i) acc[u][i] = 0.0f;
    float m_run = -INFINITY, l_run = 0.0f;

    const int jb_max = (r0 + QT - 1) >> 6;
    for (int jb = 0; jb <= jb_max; ++jb) {
        const int j0 = jb * KT;
        __syncthreads();   // previous iteration's PV reads of KV done
        // load K tile transposed: Kt[d][j]
#pragma unroll
        for (int i = 0; i < 8; ++i) {
            int flat = tid + 256 * i;   // 0..2047
            int r = flat >> 5;
            int d = (flat & 31) << 2;
            float4 t = *(const float4*)(k + (size_t)(j0 + r) * HIDDEN + h * HD + d);
            KV[(d + 0) * 68 + r] = t.x; KV[(d + 1) * 68 + r] = t.y;
            KV[(d + 2) * 68 + r] = t.z; KV[(d + 3) * 68 + r] = t.w;
        }
        __syncthreads();
        // S = (Q K^T) * scale with causal mask
        float s8[2][4] = {{0.f, 0.f, 0.f, 0.f}, {0.f, 0.f, 0.f, 0.f}};
        for (int d = 0; d < 128; ++d) {
            float2 qv = *(const float2*)&Qt[d][sy * 2];
            float4 kv4 = *(const float4*)&KV[d * 68 + sx * 4];
            s8[0][0] = fmaf(qv.x, kv4.x, s8[0][0]);
            s8[0][1] = fmaf(qv.x, kv4.y, s8[0][1]);
            s8[0][2] = fmaf(qv.x, kv4.z, s8[0][2]);
            s8[0][3] = fmaf(qv.x, kv4.w, s8[0][3]);
            s8[1][0] = fmaf(qv.y, kv4.x, s8[1][0]);
            s8[1][1] = fmaf(qv.y, kv4.y, s8[1][1]);
            s8[1][2] = fmaf(qv.y, kv4.z, s8[1][2]);
            s8[1][3] = fmaf(qv.y, kv4.w, s8[1][3]);
        }
#pragma unroll
        for (int i = 0; i < 2; ++i) {
            int gr = r0 + sy * 2 + i;
#pragma unroll
            for (int jj = 0; jj < 4; ++jj) {
                int gj = j0 + sx * 4 + jj;
                float val = s8[i][jj] * scale;
                Ps[sy * 2 + i][sx * 4 + jj] = (gj > gr) ? -INFINITY : val;
            }
        }
        __syncthreads();
        // online softmax: 8 threads per row, 8 cols each
        {
            const int c0 = (tid & 7) * 8;
            float sv[8];
            float mx = -INFINITY;
#pragma unroll
            for (int i = 0; i < 8; ++i) { sv[i] = Ps[orow][c0 + i]; mx = fmaxf(mx, sv[i]); }
            mx = fmaxf(mx, __shfl_xor(mx, 1));
            mx = fmaxf(mx, __shfl_xor(mx, 2));
            mx = fmaxf(mx, __shfl_xor(mx, 4));
            float m_new = fmaxf(m_run, mx);
            float corr = expf(m_run - m_new);      // 0 on first block
            float lsum = 0.f;
#pragma unroll
            for (int i = 0; i < 8; ++i) {
                float p = expf(sv[i] - m_new);
                Ps[orow][c0 + i] = p;
                lsum += p;
            }
            lsum += __shfl_xor(lsum, 1);
            lsum += __shfl_xor(lsum, 2);
            lsum += __shfl_xor(lsum, 4);
            l_run = l_run * corr + lsum;
            m_run = m_new;
#pragma unroll
            for (int u = 0; u < 4; ++u)
#pragma unroll
                for (int i = 0; i < 4; ++i) acc[u][i] *= corr;
        }
        __syncthreads();   // Ps probs final; KV free for V
        // load V tile row-major: Vs[j][d]
#pragma unroll
        for (int i = 0; i < 8; ++i) {
            int flat = tid + 256 * i;
            int r = flat >> 5;
            int d = (flat & 31) << 2;
            float4 t = *(const float4*)(v + (size_t)(j0 + r) * HIDDEN + h * HD + d);
            *(float4*)&KV[r * 136 + d] = t;
        }
        __syncthreads();
        // PV: out[orow][oc4 + u*32 .. +3] += P[orow][j] * V[j][...]
        for (int j = 0; j < KT; ++j) {
            float p = Ps[orow][j];
#pragma unroll
            for (int u = 0; u < 4; ++u) {
                float4 vv = *(const float4*)&KV[j * 136 + oc4 + u * 32];
                acc[u][0] = fmaf(p, vv.x, acc[u][0]);
                acc[u][1] = fmaf(p, vv.y, acc[u][1]);
                acc[u][2] = fmaf(p, vv.z, acc[u][2]);
                acc[u][3] = fmaf(p, vv.w, acc[u][3]);
            }
        }
    }

    // finalize token part
    float inv_l = 1.0f / l_run;
#pragma unroll
    for (int u = 0; u < 4; ++u)
#pragma unroll
        for (int i = 0; i < 4; ++i) acc[u][i] *= inv_l;

    // gated prefix part (separate softmax over 10 keys, no mask, no RoPE)
    {
        float g = tanhf(gate[h]);
        float sp[PLEN];
        float mp = -INFINITY;
#pragma unroll
        for (int i = 0; i < PLEN; ++i) {
            const float* kpr = kp + (size_t)i * HIDDEN + h * HD;
            float s = 0.f;
            for (int d = 0; d < 128; ++d) s = fmaf(Qt[d][orow], kpr[d], s);
            sp[i] = s * scale;
            mp = fmaxf(mp, sp[i]);
        }
        float ssum = 0.f;
#pragma unroll
        for (int i = 0; i < PLEN; ++i) { sp[i] = expf(sp[i] - mp); ssum += sp[i]; }
        float gs = g / ssum;
#pragma unroll
        for (int i = 0; i < PLEN; ++i) {
            float w = sp[i] * gs;
            const float* vpr = vp + (size_t)i * HIDDEN + h * HD;
#pragma unroll
            for (int u = 0; u < 4; ++u) {
                float4 vv = *(const float4*)(vpr + oc4 + u * 32);
                acc[u][0] = fmaf(w, vv.x, acc[u][0]);
                acc[u][1] = fmaf(w, vv.y, acc[u][1]);
                acc[u][2] = fmaf(w, vv.z, acc[u][2]);
                acc[u][3] = fmaf(w, vv.w, acc[u][3]);
            }
        }
    }

    float* op = out + (size_t)(r0 + orow) * HIDDEN + h * HD;
#pragma unroll
    for (int u = 0; u < 4; ++u)
        *(float4*)(op + oc4 + u * 32) = make_float4(acc[u][0], acc[u][1], acc[u][2], acc[u][3]);
}

extern "C" void kernel_launch(void* const* d_in, const int* in_sizes, int n_in,
                              void* d_out, int out_size, void* d_ws, size_t ws_size,
                              hipStream_t stream)
{
    (void)in_sizes; (void)n_in; (void)out_size; (void)ws_size;
    const float* hidden  = (const float*)d_in[0];
    // d_in[1] attention_mask: causal per setup, applied analytically
    const int*   pos     = (const int*)d_in[2];
    const float* Wq      = (const float*)d_in[3];
    const float* Wk      = (const float*)d_in[4];
    const float* Wv      = (const float*)d_in[5];
    const float* Wo      = (const float*)d_in[6];
    const float* adapter = (const float*)d_in[7];
    const float* gate    = (const float*)d_in[8];
    float* out = (float*)d_out;

    float* ws = (float*)d_ws;
    const size_t SH = (size_t)SEQQ * HIDDEN;     // 8,388,608 floats
    float* qb   = ws;
    float* kb   = ws + SH;
    float* vb   = ws + 2 * SH;
    float* kpb  = ws + 3 * SH;
    float* vpb  = kpb + (size_t)PLEN * HIDDEN;
    float* cosT = vpb + (size_t)PLEN * HIDDEN;
    float* sinT = cosT + (size_t)SEQQ * 64;

    rope_table_kernel<<<SEQQ, 64, 0, stream>>>(pos, cosT, sinT);

    dim3 blk(256);
    dim3 gbig(HIDDEN / 128, SEQQ / 128);
    gemm_nt_kernel<<<gbig, blk, 0, stream>>>(hidden, Wq, qb, SEQQ, HIDDEN, HIDDEN);
    gemm_nt_kernel<<<gbig, blk, 0, stream>>>(hidden, Wk, kb, SEQQ, HIDDEN, HIDDEN);
    gemm_nt_kernel<<<gbig, blk, 0, stream>>>(hidden, Wv, vb, SEQQ, HIDDEN, HIDDEN);

    dim3 gsm(HIDDEN / 128, 1);
    gemm_nt_kernel<<<gsm, blk, 0, stream>>>(adapter, Wk, kpb, PLEN, HIDDEN, HIDDEN);
    gemm_nt_kernel<<<gsm, blk, 0, stream>>>(adapter, Wv, vpb, PLEN, HIDDEN, HIDDEN);

    rope_apply_kernel<<<(SEQQ * 2048) / 256, 256, 0, stream>>>(qb, kb, cosT, sinT);

    attn_kernel<<<dim3(SEQQ / QT, NH), blk, 0, stream>>>(qb, kb, vb, kpb, vpb, gate, qb);

    gemm_nt_kernel<<<gbig, blk, 0, stream>>>(qb, Wo, out, SEQQ, HIDDEN, HIDDEN);
}

// Round 4
// 5531.029 us; speedup vs baseline: 1.1230x; 1.1230x over previous
//
#include <hip/hip_runtime.h>
#include <math.h>

#define HIDDEN 4096
#define NH 32
#define HD 128
#define PLEN 10
#define SEQQ 2048
#define QT 32
#define KT 64

typedef __attribute__((ext_vector_type(8))) short bf16x8;
typedef __attribute__((ext_vector_type(4))) float f32x4;

__device__ inline unsigned short f2bf(float f) {
    unsigned u = __float_as_uint(f);
    u += 0x7FFFu + ((u >> 16) & 1u);     // round-to-nearest-even
    return (unsigned short)(u >> 16);
}
__device__ inline float bf2f(unsigned short h) {
    return __uint_as_float(((unsigned)h) << 16);
}

// ---------------- fp32 -> (bf16 hi, bf16 lo) planes, 8 elems/thread ----------------
__global__ __launch_bounds__(256) void convert_hilo_kernel(
    const float* __restrict__ x, unsigned short* __restrict__ hi,
    unsigned short* __restrict__ lo, int n8)
{
    int idx = blockIdx.x * 256 + threadIdx.x;
    if (idx >= n8) return;
    const float4* xp = (const float4*)x;
    float4 a = xp[idx * 2], b = xp[idx * 2 + 1];
    float v[8] = {a.x, a.y, a.z, a.w, b.x, b.y, b.z, b.w};
    unsigned hu[4], lu[4];
#pragma unroll
    for (int i = 0; i < 4; ++i) {
        unsigned short h0 = f2bf(v[2 * i]);
        unsigned short l0 = f2bf(v[2 * i] - bf2f(h0));
        unsigned short h1 = f2bf(v[2 * i + 1]);
        unsigned short l1 = f2bf(v[2 * i + 1] - bf2f(h1));
        hu[i] = (unsigned)h0 | ((unsigned)h1 << 16);
        lu[i] = (unsigned)l0 | ((unsigned)l1 << 16);
    }
    ((uint4*)hi)[idx] = make_uint4(hu[0], hu[1], hu[2], hu[3]);
    ((uint4*)lo)[idx] = make_uint4(lu[0], lu[1], lu[2], lu[3]);
}

// ---------------- split-bf16 MFMA GEMM NT: C[M,N] = A[M,K] * B[N,K]^T ----------------
// 128x128 tile, BK=32, 256 threads = 4 waves, each wave 64x64 (4x4 16x16 frags).
// C ~= Ahi*Bhi + Ahi*Blo + Alo*Bhi  (fp32 accumulate; ~fp32 accuracy)
__global__ __launch_bounds__(256) void gemm_mfma_split_kernel(
    const unsigned short* __restrict__ Ahi, const unsigned short* __restrict__ Alo,
    const unsigned short* __restrict__ Bhi, const unsigned short* __restrict__ Blo,
    float* __restrict__ C, int M, int N, int K)
{
    __shared__ short sA[2][128 * 40];   // [hi/lo][row*40 + k], +8 shorts row pad
    __shared__ short sB[2][128 * 40];
    const int tid = threadIdx.x;
    const int lane = tid & 63;
    const int wave = tid >> 6;
    const int wm = (wave >> 1) * 64;
    const int wn = (wave & 1) * 64;
    const int lr = lane & 15;
    const int lq = lane >> 4;
    const int m0 = blockIdx.y * 128;
    const int n0 = blockIdx.x * 128;

    // staging: 512 chunks of 16B per tile; thread handles rows r0 and r0+64
    const int r0 = tid >> 2;
    const int c0 = (tid & 3) * 8;
    const size_t a0 = (size_t)(m0 + r0) * K + c0;
    const size_t a1 = (size_t)(m0 + r0 + 64) * K + c0;
    const size_t b0 = (size_t)(n0 + r0) * K + c0;
    const size_t b1 = (size_t)(n0 + r0 + 64) * K + c0;
    const int w0 = r0 * 40 + c0;
    const int w1 = (r0 + 64) * 40 + c0;

    f32x4 acc[4][4];
#pragma unroll
    for (int m = 0; m < 4; ++m)
#pragma unroll
        for (int n = 0; n < 4; ++n) acc[m][n] = (f32x4){0.f, 0.f, 0.f, 0.f};

    uint4 st[8];
#define GLOAD(k0) do { \
        st[0] = *(const uint4*)(Ahi + a0 + (k0)); st[1] = *(const uint4*)(Ahi + a1 + (k0)); \
        st[2] = *(const uint4*)(Alo + a0 + (k0)); st[3] = *(const uint4*)(Alo + a1 + (k0)); \
        st[4] = *(const uint4*)(Bhi + b0 + (k0)); st[5] = *(const uint4*)(Bhi + b1 + (k0)); \
        st[6] = *(const uint4*)(Blo + b0 + (k0)); st[7] = *(const uint4*)(Blo + b1 + (k0)); \
    } while (0)

    GLOAD(0);
    const int NK = K >> 5;
    for (int ks = 0; ks < NK; ++ks) {
        __syncthreads();               // previous iteration's frag reads done
        *(uint4*)&sA[0][w0] = st[0];  *(uint4*)&sA[0][w1] = st[1];
        *(uint4*)&sA[1][w0] = st[2];  *(uint4*)&sA[1][w1] = st[3];
        *(uint4*)&sB[0][w0] = st[4];  *(uint4*)&sB[0][w1] = st[5];
        *(uint4*)&sB[1][w0] = st[6];  *(uint4*)&sB[1][w1] = st[7];
        __syncthreads();
        if (ks + 1 < NK) GLOAD((ks + 1) << 5);   // next-step loads fly during MFMAs

        bf16x8 ah[4], al[4], bh[4], bl[4];
#pragma unroll
        for (int m = 0; m < 4; ++m) {
            int ro = (wm + m * 16 + lr) * 40 + lq * 8;
            ah[m] = *(const bf16x8*)&sA[0][ro];
            al[m] = *(const bf16x8*)&sA[1][ro];
        }
#pragma unroll
        for (int n = 0; n < 4; ++n) {
            int ro = (wn + n * 16 + lr) * 40 + lq * 8;
            bh[n] = *(const bf16x8*)&sB[0][ro];
            bl[n] = *(const bf16x8*)&sB[1][ro];
        }
#pragma unroll
        for (int m = 0; m < 4; ++m)
#pragma unroll
            for (int n = 0; n < 4; ++n) {
                acc[m][n] = __builtin_amdgcn_mfma_f32_16x16x32_bf16(ah[m], bh[n], acc[m][n], 0, 0, 0);
                acc[m][n] = __builtin_amdgcn_mfma_f32_16x16x32_bf16(ah[m], bl[n], acc[m][n], 0, 0, 0);
                acc[m][n] = __builtin_amdgcn_mfma_f32_16x16x32_bf16(al[m], bh[n], acc[m][n], 0, 0, 0);
            }
    }
#undef GLOAD

#pragma unroll
    for (int m = 0; m < 4; ++m) {
        const int row = m0 + wm + m * 16 + lq * 4;
#pragma unroll
        for (int n = 0; n < 4; ++n) {
            const int col = n0 + wn + n * 16 + lr;
#pragma unroll
            for (int j = 0; j < 4; ++j)
                C[(size_t)(row + j) * N + col] = acc[m][n][j];
        }
    }
}

// ---------------- RoPE cos/sin tables ----------------
__global__ void rope_table_kernel(const int* __restrict__ pos,
                                  float* __restrict__ cosT, float* __restrict__ sinT)
{
    int s = blockIdx.x;
    int j = threadIdx.x;               // 0..63
    float p = (float)pos[s];
    float expnt = (2.0f * (float)j) * (1.0f / 128.0f);
    float inv_freq = powf(10000.0f, -expnt);
    float f = p * inv_freq;
    cosT[s * 64 + j] = cosf(f);
    sinT[s * 64 + j] = sinf(f);
}

// ---------------- fp32 GEMM NT (adapter path + ws fallback) ----------------
__global__ __launch_bounds__(256) void gemm_nt_kernel(
    const float* __restrict__ A, const float* __restrict__ B, float* __restrict__ C,
    int M, int N, int K)
{
    __shared__ float As[8][132];
    __shared__ float Bs[8][132];
    const int tid = threadIdx.x;
    const int tx = tid & 15, ty = tid >> 4;
    const int m0 = blockIdx.y * 128, n0 = blockIdx.x * 128;
    const int lr = tid >> 1;
    const int lk = (tid & 1) * 4;
    const bool aval = (m0 + lr) < M;
    const float* Ap = A + (size_t)(m0 + lr) * K + lk;
    const float* Bp = B + (size_t)(n0 + lr) * K + lk;

    float acc[8][8];
#pragma unroll
    for (int i = 0; i < 8; ++i)
#pragma unroll
        for (int j = 0; j < 8; ++j) acc[i][j] = 0.0f;

    for (int k0 = 0; k0 < K; k0 += 8) {
        float4 a4 = make_float4(0.f, 0.f, 0.f, 0.f);
        if (aval) a4 = *(const float4*)(Ap + k0);
        float4 b4 = *(const float4*)(Bp + k0);
        __syncthreads();
        As[lk + 0][lr] = a4.x; As[lk + 1][lr] = a4.y; As[lk + 2][lr] = a4.z; As[lk + 3][lr] = a4.w;
        Bs[lk + 0][lr] = b4.x; Bs[lk + 1][lr] = b4.y; Bs[lk + 2][lr] = b4.z; Bs[lk + 3][lr] = b4.w;
        __syncthreads();
#pragma unroll
        for (int kk = 0; kk < 8; ++kk) {
            float4 a0 = *(const float4*)&As[kk][ty * 8];
            float4 a1 = *(const float4*)&As[kk][ty * 8 + 4];
            float4 b0 = *(const float4*)&Bs[kk][tx * 8];
            float4 b1 = *(const float4*)&Bs[kk][tx * 8 + 4];
            float a[8] = {a0.x, a0.y, a0.z, a0.w, a1.x, a1.y, a1.z, a1.w};
            float b[8] = {b0.x, b0.y, b0.z, b0.w, b1.x, b1.y, b1.z, b1.w};
#pragma unroll
            for (int i = 0; i < 8; ++i)
#pragma unroll
                for (int j = 0; j < 8; ++j)
                    acc[i][j] = fmaf(a[i], b[j], acc[i][j]);
        }
    }
#pragma unroll
    for (int i = 0; i < 8; ++i) {
        int row = m0 + ty * 8 + i;
        if (row < M) {
            float* Cp = C + (size_t)row * N + n0 + tx * 8;
            *(float4*)Cp       = make_float4(acc[i][0], acc[i][1], acc[i][2], acc[i][3]);
            *(float4*)(Cp + 4) = make_float4(acc[i][4], acc[i][5], acc[i][6], acc[i][7]);
        }
    }
}

// ---------------- RoPE apply in place on q and k ----------------
__global__ void rope_apply_kernel(float* __restrict__ q, float* __restrict__ k,
                                  const float* __restrict__ cosT, const float* __restrict__ sinT)
{
    int idx = blockIdx.x * 256 + threadIdx.x;
    int s = idx >> 11;
    int rem = idx & 2047;
    int h = rem >> 6;
    int d = rem & 63;
    float c = cosT[s * 64 + d], sn = sinT[s * 64 + d];
    size_t base = (size_t)s * HIDDEN + h * HD + d;
    float a = q[base], b = q[base + 64];
    q[base]      = a * c - b * sn;
    q[base + 64] = b * c + a * sn;
    a = k[base]; b = k[base + 64];
    k[base]      = a * c - b * sn;
    k[base + 64] = b * c + a * sn;
}

// ---------------- fused attention (token flash + gated prefix) ----------------
__global__ __launch_bounds__(256) void attn_kernel(
    const float* __restrict__ q, const float* __restrict__ k, const float* __restrict__ v,
    const float* __restrict__ kp, const float* __restrict__ vp,
    const float* __restrict__ gate, float* __restrict__ out)
{
    __shared__ float Qt[128][36];
    __shared__ float KV[128 * 68];
    __shared__ float Ps[QT][68];

    const int h = blockIdx.y;
    const int r0 = blockIdx.x * QT;
    const int tid = threadIdx.x;
    const int orow = tid >> 3;
    const int oc4 = (tid & 7) * 4;
    const int sy = tid >> 4;
    const int sx = tid & 15;
    const float scale = 0.088388347648318447f;

#pragma unroll
    for (int i = 0; i < 4; ++i) {
        int flat = tid + 256 * i;
        int r = flat >> 5;
        int d = (flat & 31) << 2;
        float4 t = *(const float4*)(q + (size_t)(r0 + r) * HIDDEN + h * HD + d);
        Qt[d + 0][r] = t.x; Qt[d + 1][r] = t.y; Qt[d + 2][r] = t.z; Qt[d + 3][r] = t.w;
    }

    float acc[4][4];
#pragma unroll
    for (int u = 0; u < 4; ++u)
#pragma unroll
        for (int i = 0; i < 4; ++i) acc[u][i] = 0.0f;
    float m_run = -INFINITY, l_run = 0.0f;

    const int jb_max = (r0 + QT - 1) >> 6;
    for (int jb = 0; jb <= jb_max; ++jb) {
        const int j0 = jb * KT;
        __syncthreads();
#pragma unroll
        for (int i = 0; i < 8; ++i) {
            int flat = tid + 256 * i;
            int r = flat >> 5;
            int d = (flat & 31) << 2;
            float4 t = *(const float4*)(k + (size_t)(j0 + r) * HIDDEN + h * HD + d);
            KV[(d + 0) * 68 + r] = t.x; KV[(d + 1) * 68 + r] = t.y;
            KV[(d + 2) * 68 + r] = t.z; KV[(d + 3) * 68 + r] = t.w;
        }
        __syncthreads();
        float s8[2][4] = {{0.f, 0.f, 0.f, 0.f}, {0.f, 0.f, 0.f, 0.f}};
        for (int d = 0; d < 128; ++d) {
            float2 qv = *(const float2*)&Qt[d][sy * 2];
            float4 kv4 = *(const float4*)&KV[d * 68 + sx * 4];
            s8[0][0] = fmaf(qv.x, kv4.x, s8[0][0]);
            s8[0][1] = fmaf(qv.x, kv4.y, s8[0][1]);
            s8[0][2] = fmaf(qv.x, kv4.z, s8[0][2]);
            s8[0][3] = fmaf(qv.x, kv4.w, s8[0][3]);
            s8[1][0] = fmaf(qv.y, kv4.x, s8[1][0]);
            s8[1][1] = fmaf(qv.y, kv4.y, s8[1][1]);
            s8[1][2] = fmaf(qv.y, kv4.z, s8[1][2]);
            s8[1][3] = fmaf(qv.y, kv4.w, s8[1][3]);
        }
#pragma unroll
        for (int i = 0; i < 2; ++i) {
            int gr = r0 + sy * 2 + i;
#pragma unroll
            for (int jj = 0; jj < 4; ++jj) {
                int gj = j0 + sx * 4 + jj;
                float val = s8[i][jj] * scale;
                Ps[sy * 2 + i][sx * 4 + jj] = (gj > gr) ? -INFINITY : val;
            }
        }
        __syncthreads();
        {
            const int c0 = (tid & 7) * 8;
            float sv[8];
            float mx = -INFINITY;
#pragma unroll
            for (int i = 0; i < 8; ++i) { sv[i] = Ps[orow][c0 + i]; mx = fmaxf(mx, sv[i]); }
            mx = fmaxf(mx, __shfl_xor(mx, 1));
            mx = fmaxf(mx, __shfl_xor(mx, 2));
            mx = fmaxf(mx, __shfl_xor(mx, 4));
            float m_new = fmaxf(m_run, mx);
            float corr = expf(m_run - m_new);
            float lsum = 0.f;
#pragma unroll
            for (int i = 0; i < 8; ++i) {
                float p = expf(sv[i] - m_new);
                Ps[orow][c0 + i] = p;
                lsum += p;
            }
            lsum += __shfl_xor(lsum, 1);
            lsum += __shfl_xor(lsum, 2);
            lsum += __shfl_xor(lsum, 4);
            l_run = l_run * corr + lsum;
            m_run = m_new;
#pragma unroll
            for (int u = 0; u < 4; ++u)
#pragma unroll
                for (int i = 0; i < 4; ++i) acc[u][i] *= corr;
        }
        __syncthreads();
#pragma unroll
        for (int i = 0; i < 8; ++i) {
            int flat = tid + 256 * i;
            int r = flat >> 5;
            int d = (flat & 31) << 2;
            float4 t = *(const float4*)(v + (size_t)(j0 + r) * HIDDEN + h * HD + d);
            *(float4*)&KV[r * 136 + d] = t;
        }
        __syncthreads();
        for (int j = 0; j < KT; ++j) {
            float p = Ps[orow][j];
#pragma unroll
            for (int u = 0; u < 4; ++u) {
                float4 vv = *(const float4*)&KV[j * 136 + oc4 + u * 32];
                acc[u][0] = fmaf(p, vv.x, acc[u][0]);
                acc[u][1] = fmaf(p, vv.y, acc[u][1]);
                acc[u][2] = fmaf(p, vv.z, acc[u][2]);
                acc[u][3] = fmaf(p, vv.w, acc[u][3]);
            }
        }
    }

    float inv_l = 1.0f / l_run;
#pragma unroll
    for (int u = 0; u < 4; ++u)
#pragma unroll
        for (int i = 0; i < 4; ++i) acc[u][i] *= inv_l;

    {
        float g = tanhf(gate[h]);
        float sp[PLEN];
        float mp = -INFINITY;
#pragma unroll
        for (int i = 0; i < PLEN; ++i) {
            const float* kpr = kp + (size_t)i * HIDDEN + h * HD;
            float s = 0.f;
            for (int d = 0; d < 128; ++d) s = fmaf(Qt[d][orow], kpr[d], s);
            sp[i] = s * scale;
            mp = fmaxf(mp, sp[i]);
        }
        float ssum = 0.f;
#pragma unroll
        for (int i = 0; i < PLEN; ++i) { sp[i] = expf(sp[i] - mp); ssum += sp[i]; }
        float gs = g / ssum;
#pragma unroll
        for (int i = 0; i < PLEN; ++i) {
            float w = sp[i] * gs;
            const float* vpr = vp + (size_t)i * HIDDEN + h * HD;
#pragma unroll
            for (int u = 0; u < 4; ++u) {
                float4 vv = *(const float4*)(vpr + oc4 + u * 32);
                acc[u][0] = fmaf(w, vv.x, acc[u][0]);
                acc[u][1] = fmaf(w, vv.y, acc[u][1]);
                acc[u][2] = fmaf(w, vv.z, acc[u][2]);
                acc[u][3] = fmaf(w, vv.w, acc[u][3]);
            }
        }
    }

    float* op = out + (size_t)(r0 + orow) * HIDDEN + h * HD;
#pragma unroll
    for (int u = 0; u < 4; ++u)
        *(float4*)(op + oc4 + u * 32) = make_float4(acc[u][0], acc[u][1], acc[u][2], acc[u][3]);
}

extern "C" void kernel_launch(void* const* d_in, const int* in_sizes, int n_in,
                              void* d_out, int out_size, void* d_ws, size_t ws_size,
                              hipStream_t stream)
{
    (void)in_sizes; (void)n_in; (void)out_size;
    const float* hidden  = (const float*)d_in[0];
    const int*   pos     = (const int*)d_in[2];
    const float* Wq      = (const float*)d_in[3];
    const float* Wk      = (const float*)d_in[4];
    const float* Wv      = (const float*)d_in[5];
    const float* Wo      = (const float*)d_in[6];
    const float* adapter = (const float*)d_in[7];
    const float* gate    = (const float*)d_in[8];
    float* out = (float*)d_out;

    float* ws = (float*)d_ws;
    const size_t SH = (size_t)SEQQ * HIDDEN;          // 8,388,608
    const size_t WN = (size_t)HIDDEN * HIDDEN;        // 16,777,216
    float* qb   = ws;
    float* kb   = ws + SH;
    float* vb   = ws + 2 * SH;
    float* kpb  = ws + 3 * SH;
    float* vpb  = kpb + (size_t)PLEN * HIDDEN;
    float* cosT = vpb + (size_t)PLEN * HIDDEN;
    float* sinT = cosT + (size_t)SEQQ * 64;
    unsigned short* Hhi = (unsigned short*)(sinT + (size_t)SEQQ * 64);
    unsigned short* Hlo = Hhi + SH;
    unsigned short* Whi = Hlo + SH;
    unsigned short* Wlo = Whi + WN;
    const size_t need = (size_t)((char*)(Wlo + WN) - (char*)d_ws);
    const bool use_mfma = (ws_size >= need);

    rope_table_kernel<<<SEQQ, 64, 0, stream>>>(pos, cosT, sinT);

    dim3 blk(256);
    dim3 gbig(HIDDEN / 128, SEQQ / 128);
    const int nH8 = (int)(SH / 8);   // 1,048,576
    const int nW8 = (int)(WN / 8);   // 2,097,152

    if (use_mfma) {
        convert_hilo_kernel<<<nH8 / 256, blk, 0, stream>>>(hidden, Hhi, Hlo, nH8);
        convert_hilo_kernel<<<nW8 / 256, blk, 0, stream>>>(Wq, Whi, Wlo, nW8);
        gemm_mfma_split_kernel<<<gbig, blk, 0, stream>>>(Hhi, Hlo, Whi, Wlo, qb, SEQQ, HIDDEN, HIDDEN);
        convert_hilo_kernel<<<nW8 / 256, blk, 0, stream>>>(Wk, Whi, Wlo, nW8);
        gemm_mfma_split_kernel<<<gbig, blk, 0, stream>>>(Hhi, Hlo, Whi, Wlo, kb, SEQQ, HIDDEN, HIDDEN);
        convert_hilo_kernel<<<nW8 / 256, blk, 0, stream>>>(Wv, Whi, Wlo, nW8);
        gemm_mfma_split_kernel<<<gbig, blk, 0, stream>>>(Hhi, Hlo, Whi, Wlo, vb, SEQQ, HIDDEN, HIDDEN);
    } else {
        gemm_nt_kernel<<<gbig, blk, 0, stream>>>(hidden, Wq, qb, SEQQ, HIDDEN, HIDDEN);
        gemm_nt_kernel<<<gbig, blk, 0, stream>>>(hidden, Wk, kb, SEQQ, HIDDEN, HIDDEN);
        gemm_nt_kernel<<<gbig, blk, 0, stream>>>(hidden, Wv, vb, SEQQ, HIDDEN, HIDDEN);
    }

    dim3 gsm(HIDDEN / 128, 1);
    gemm_nt_kernel<<<gsm, blk, 0, stream>>>(adapter, Wk, kpb, PLEN, HIDDEN, HIDDEN);
    gemm_nt_kernel<<<gsm, blk, 0, stream>>>(adapter, Wv, vpb, PLEN, HIDDEN, HIDDEN);

    rope_apply_kernel<<<(SEQQ * 2048) / 256, 256, 0, stream>>>(qb, kb, cosT, sinT);

    attn_kernel<<<dim3(SEQQ / QT, NH), blk, 0, stream>>>(qb, kb, vb, kpb, vpb, gate, qb);

    if (use_mfma) {
        convert_hilo_kernel<<<nH8 / 256, blk, 0, stream>>>(qb, Hhi, Hlo, nH8);
        convert_hilo_kernel<<<nW8 / 256, blk, 0, stream>>>(Wo, Whi, Wlo, nW8);
        gemm_mfma_split_kernel<<<gbig, blk, 0, stream>>>(Hhi, Hlo, Whi, Wlo, out, SEQQ, HIDDEN, HIDDEN);
    } else {
        gemm_nt_kernel<<<gbig, blk, 0, stream>>>(qb, Wo, out, SEQQ, HIDDEN, HIDDEN);
    }
}

// Round 5
// 2651.959 us; speedup vs baseline: 2.3422x; 2.0856x over previous
//
#include <hip/hip_runtime.h>
#include <math.h>

#define HIDDEN 4096
#define NH 32
#define HD 128
#define PLEN 10
#define SEQQ 2048
#define QT 32
#define KT 64

typedef __attribute__((ext_vector_type(8))) short bf16x8;
typedef __attribute__((ext_vector_type(4))) float f32x4;
typedef unsigned short ushort_t;

__device__ inline unsigned short f2bf(float f) {
    unsigned u = __float_as_uint(f);
    u += 0x7FFFu + ((u >> 16) & 1u);     // round-to-nearest-even
    return (unsigned short)(u >> 16);
}
__device__ inline float bf2f(unsigned short h) {
    return __uint_as_float(((unsigned)h) << 16);
}

// async global->LDS, 16 bytes per lane; LDS dest is wave-uniform base + lane*16
#define GLD16(g, l) __builtin_amdgcn_global_load_lds( \
        (const __attribute__((address_space(1))) void*)(g), \
        (__attribute__((address_space(3))) void*)(l), 16, 0, 0)

// ---------------- fp32 -> (bf16 hi, bf16 lo) planes, 8 elems/thread ----------------
__global__ __launch_bounds__(256) void convert_hilo_kernel(
    const float* __restrict__ x, ushort_t* __restrict__ hi,
    ushort_t* __restrict__ lo, int n8)
{
    int idx = blockIdx.x * 256 + threadIdx.x;
    if (idx >= n8) return;
    const float4* xp = (const float4*)x;
    float4 a = xp[idx * 2], b = xp[idx * 2 + 1];
    float v[8] = {a.x, a.y, a.z, a.w, b.x, b.y, b.z, b.w};
    unsigned hu[4], lu[4];
#pragma unroll
    for (int i = 0; i < 4; ++i) {
        unsigned short h0 = f2bf(v[2 * i]);
        unsigned short l0 = f2bf(v[2 * i] - bf2f(h0));
        unsigned short h1 = f2bf(v[2 * i + 1]);
        unsigned short l1 = f2bf(v[2 * i + 1] - bf2f(h1));
        hu[i] = (unsigned)h0 | ((unsigned)h1 << 16);
        lu[i] = (unsigned)l0 | ((unsigned)l1 << 16);
    }
    ((uint4*)hi)[idx] = make_uint4(hu[0], hu[1], hu[2], hu[3]);
    ((uint4*)lo)[idx] = make_uint4(lu[0], lu[1], lu[2], lu[3]);
}

// ---------------- adapter (10x4096) -> zero-padded 128x4096 hi/lo planes ----------------
__global__ __launch_bounds__(256) void convert_pad_kernel(
    const float* __restrict__ src, ushort_t* __restrict__ hi, ushort_t* __restrict__ lo)
{
    int idx = blockIdx.x * 256 + threadIdx.x;   // 65536 chunks of 8 elems
    int row = idx >> 9;                          // 512 chunks per row
    unsigned hu[4], lu[4];
    if (row < PLEN) {
        const float4* xp = (const float4*)src;
        float4 a = xp[idx * 2], b = xp[idx * 2 + 1];
        float v[8] = {a.x, a.y, a.z, a.w, b.x, b.y, b.z, b.w};
#pragma unroll
        for (int i = 0; i < 4; ++i) {
            unsigned short h0 = f2bf(v[2 * i]);
            unsigned short l0 = f2bf(v[2 * i] - bf2f(h0));
            unsigned short h1 = f2bf(v[2 * i + 1]);
            unsigned short l1 = f2bf(v[2 * i + 1] - bf2f(h1));
            hu[i] = (unsigned)h0 | ((unsigned)h1 << 16);
            lu[i] = (unsigned)l0 | ((unsigned)l1 << 16);
        }
    } else {
#pragma unroll
        for (int i = 0; i < 4; ++i) { hu[i] = 0u; lu[i] = 0u; }
    }
    ((uint4*)hi)[idx] = make_uint4(hu[0], hu[1], hu[2], hu[3]);
    ((uint4*)lo)[idx] = make_uint4(lu[0], lu[1], lu[2], lu[3]);
}

// ---------------- split-bf16 MFMA GEMM NT (m97 structure) ----------------
// C[M,N] ~= Ahi*Bhi^T + Ahi*Blo^T + Alo*Bhi^T, fp32 accumulate (~fp32 accuracy).
// 128x128 tile, BK=32, 256 threads = 4 waves; wave w stages plane w via global_load_lds;
// XOR slot-swizzle (both sides: pre-swizzled global source + swizzled ds_read).
__global__ __launch_bounds__(256) void gemm_mfma_split_kernel(
    const ushort_t* __restrict__ Ahi, const ushort_t* __restrict__ Alo,
    const ushort_t* __restrict__ Bhi, const ushort_t* __restrict__ Blo,
    float* __restrict__ C, int M, int N, int K, int Mstore)
{
    __shared__ short lds[4 * 4096];     // planes: 0 Ahi, 1 Alo, 2 Bhi, 3 Blo; each [128][32]

    const int tid = threadIdx.x;
    const int lane = tid & 63;
    const int wave = tid >> 6;

    // XCD-aware bijective swizzle (nwg % 8 == 0 for all our grids)
    const int gx = gridDim.x;
    const int nwg = gx * gridDim.y;
    const int flat = blockIdx.y * gx + blockIdx.x;
    const int cpx = nwg >> 3;
    const int sw = (flat & 7) * cpx + (flat >> 3);
    const int m0 = (sw / gx) * 128;
    const int n0 = (sw % gx) * 128;

    // ---- staging setup: wave w stages plane w (8 KB = 8 chunks of 1 KB) ----
    const ushort_t* src = (wave == 0) ? Ahi : (wave == 1) ? Alo : (wave == 2) ? Bhi : Blo;
    const int tb = (wave < 2) ? m0 : n0;
    // lane's row-in-chunk = lane>>2 ; global col slot pre-swizzled by s = (bits2-3)^(bits4-5)
    const int sl_st = ((lane >> 2) & 3) ^ ((lane >> 4) & 3);
    const ushort_t* p0 = src + (size_t)(tb + (lane >> 2)) * K + (((lane & 3) ^ sl_st) << 3);
    short* ldsw = &lds[wave * 4096];

    // ---- fragment setup ----
    const int lr = lane & 15;
    const int lq = lane >> 4;
    const int wm = (wave >> 1) * 64;
    const int wn = (wave & 1) * 64;
    const int sl_rd = (lr & 3) ^ ((lr >> 2) & 3);
    const int slot = ((lq ^ sl_rd) << 3);          // shorts

    f32x4 acc[4][4];
#pragma unroll
    for (int m = 0; m < 4; ++m)
#pragma unroll
        for (int n = 0; n < 4; ++n) acc[m][n] = (f32x4){0.f, 0.f, 0.f, 0.f};

    // prologue: stage K-tile 0
#pragma unroll
    for (int c = 0; c < 8; ++c)
        GLD16(p0 + (size_t)c * 16 * K, ldsw + c * 512);

    const int NK = K >> 5;
    for (int ks = 0; ks < NK; ++ks) {
        __syncthreads();     // drains vmcnt -> tile ks resident & visible

        bf16x8 ah[4], al[4], bh[4], bl[4];
#pragma unroll
        for (int m = 0; m < 4; ++m) {
            int off = ((wm + m * 16 + lr) << 5) + slot;
            ah[m] = *(const bf16x8*)&lds[off];
            al[m] = *(const bf16x8*)&lds[4096 + off];
        }
#pragma unroll
        for (int n = 0; n < 4; ++n) {
            int off = ((wn + n * 16 + lr) << 5) + slot;
            bh[n] = *(const bf16x8*)&lds[8192 + off];
            bl[n] = *(const bf16x8*)&lds[12288 + off];
        }
#pragma unroll
        for (int m = 0; m < 4; ++m)
#pragma unroll
            for (int n = 0; n < 4; ++n) {
                acc[m][n] = __builtin_amdgcn_mfma_f32_16x16x32_bf16(ah[m], bh[n], acc[m][n], 0, 0, 0);
                acc[m][n] = __builtin_amdgcn_mfma_f32_16x16x32_bf16(ah[m], bl[n], acc[m][n], 0, 0, 0);
                acc[m][n] = __builtin_amdgcn_mfma_f32_16x16x32_bf16(al[m], bh[n], acc[m][n], 0, 0, 0);
            }

        __syncthreads();     // all waves done reading LDS
        if (ks + 1 < NK) {
            const int k0 = (ks + 1) << 5;
#pragma unroll
            for (int c = 0; c < 8; ++c)
                GLD16(p0 + (size_t)c * 16 * K + k0, ldsw + c * 512);
        }
    }

    // epilogue: C layout col=lane&15, row=(lane>>4)*4+j (verified)
#pragma unroll
    for (int m = 0; m < 4; ++m) {
        const int row = m0 + wm + m * 16 + lq * 4;
#pragma unroll
        for (int n = 0; n < 4; ++n) {
            const int col = n0 + wn + n * 16 + lr;
#pragma unroll
            for (int j = 0; j < 4; ++j)
                if (row + j < Mstore)
                    C[(size_t)(row + j) * N + col] = acc[m][n][j];
        }
    }
}

// ---------------- RoPE cos/sin tables ----------------
__global__ void rope_table_kernel(const int* __restrict__ pos,
                                  float* __restrict__ cosT, float* __restrict__ sinT)
{
    int s = blockIdx.x;
    int j = threadIdx.x;               // 0..63
    float p = (float)pos[s];
    float expnt = (2.0f * (float)j) * (1.0f / 128.0f);
    float inv_freq = powf(10000.0f, -expnt);
    float f = p * inv_freq;
    cosT[s * 64 + j] = cosf(f);
    sinT[s * 64 + j] = sinf(f);
}

// ---------------- fp32 GEMM NT (ws-too-small fallback only) ----------------
__global__ __launch_bounds__(256) void gemm_nt_kernel(
    const float* __restrict__ A, const float* __restrict__ B, float* __restrict__ C,
    int M, int N, int K)
{
    __shared__ float As[8][132];
    __shared__ float Bs[8][132];
    const int tid = threadIdx.x;
    const int tx = tid & 15, ty = tid >> 4;
    const int m0 = blockIdx.y * 128, n0 = blockIdx.x * 128;
    const int lr = tid >> 1;
    const int lk = (tid & 1) * 4;
    const bool aval = (m0 + lr) < M;
    const float* Ap = A + (size_t)(m0 + lr) * K + lk;
    const float* Bp = B + (size_t)(n0 + lr) * K + lk;

    float acc[8][8];
#pragma unroll
    for (int i = 0; i < 8; ++i)
#pragma unroll
        for (int j = 0; j < 8; ++j) acc[i][j] = 0.0f;

    for (int k0 = 0; k0 < K; k0 += 8) {
        float4 a4 = make_float4(0.f, 0.f, 0.f, 0.f);
        if (aval) a4 = *(const float4*)(Ap + k0);
        float4 b4 = *(const float4*)(Bp + k0);
        __syncthreads();
        As[lk + 0][lr] = a4.x; As[lk + 1][lr] = a4.y; As[lk + 2][lr] = a4.z; As[lk + 3][lr] = a4.w;
        Bs[lk + 0][lr] = b4.x; Bs[lk + 1][lr] = b4.y; Bs[lk + 2][lr] = b4.z; Bs[lk + 3][lr] = b4.w;
        __syncthreads();
#pragma unroll
        for (int kk = 0; kk < 8; ++kk) {
            float4 a0 = *(const float4*)&As[kk][ty * 8];
            float4 a1 = *(const float4*)&As[kk][ty * 8 + 4];
            float4 b0 = *(const float4*)&Bs[kk][tx * 8];
            float4 b1 = *(const float4*)&Bs[kk][tx * 8 + 4];
            float a[8] = {a0.x, a0.y, a0.z, a0.w, a1.x, a1.y, a1.z, a1.w};
            float b[8] = {b0.x, b0.y, b0.z, b0.w, b1.x, b1.y, b1.z, b1.w};
#pragma unroll
            for (int i = 0; i < 8; ++i)
#pragma unroll
                for (int j = 0; j < 8; ++j)
                    acc[i][j] = fmaf(a[i], b[j], acc[i][j]);
        }
    }
#pragma unroll
    for (int i = 0; i < 8; ++i) {
        int row = m0 + ty * 8 + i;
        if (row < M) {
            float* Cp = C + (size_t)row * N + n0 + tx * 8;
            *(float4*)Cp       = make_float4(acc[i][0], acc[i][1], acc[i][2], acc[i][3]);
            *(float4*)(Cp + 4) = make_float4(acc[i][4], acc[i][5], acc[i][6], acc[i][7]);
        }
    }
}

// ---------------- RoPE apply in place on q and k ----------------
__global__ void rope_apply_kernel(float* __restrict__ q, float* __restrict__ k,
                                  const float* __restrict__ cosT, const float* __restrict__ sinT)
{
    int idx = blockIdx.x * 256 + threadIdx.x;
    int s = idx >> 11;
    int rem = idx & 2047;
    int h = rem >> 6;
    int d = rem & 63;
    float c = cosT[s * 64 + d], sn = sinT[s * 64 + d];
    size_t base = (size_t)s * HIDDEN + h * HD + d;
    float a = q[base], b = q[base + 64];
    q[base]      = a * c - b * sn;
    q[base + 64] = b * c + a * sn;
    a = k[base]; b = k[base + 64];
    k[base]      = a * c - b * sn;
    k[base + 64] = b * c + a * sn;
}

// ---------------- fused attention (token flash + gated prefix) ----------------
__global__ __launch_bounds__(256) void attn_kernel(
    const float* __restrict__ q, const float* __restrict__ k, const float* __restrict__ v,
    const float* __restrict__ kp, const float* __restrict__ vp,
    const float* __restrict__ gate, float* __restrict__ out)
{
    __shared__ float Qt[128][36];
    __shared__ float KV[128 * 68];
    __shared__ float Ps[QT][68];

    const int h = blockIdx.y;
    const int r0 = blockIdx.x * QT;
    const int tid = threadIdx.x;
    const int orow = tid >> 3;
    const int oc4 = (tid & 7) * 4;
    const int sy = tid >> 4;
    const int sx = tid & 15;
    const float scale = 0.088388347648318447f;

#pragma unroll
    for (int i = 0; i < 4; ++i) {
        int flat = tid + 256 * i;
        int r = flat >> 5;
        int d = (flat & 31) << 2;
        float4 t = *(const float4*)(q + (size_t)(r0 + r) * HIDDEN + h * HD + d);
        Qt[d + 0][r] = t.x; Qt[d + 1][r] = t.y; Qt[d + 2][r] = t.z; Qt[d + 3][r] = t.w;
    }

    float acc[4][4];
#pragma unroll
    for (int u = 0; u < 4; ++u)
#pragma unroll
        for (int i = 0; i < 4; ++i) acc[u][i] = 0.0f;
    float m_run = -INFINITY, l_run = 0.0f;

    const int jb_max = (r0 + QT - 1) >> 6;
    for (int jb = 0; jb <= jb_max; ++jb) {
        const int j0 = jb * KT;
        __syncthreads();
#pragma unroll
        for (int i = 0; i < 8; ++i) {
            int flat = tid + 256 * i;
            int r = flat >> 5;
            int d = (flat & 31) << 2;
            float4 t = *(const float4*)(k + (size_t)(j0 + r) * HIDDEN + h * HD + d);
            KV[(d + 0) * 68 + r] = t.x; KV[(d + 1) * 68 + r] = t.y;
            KV[(d + 2) * 68 + r] = t.z; KV[(d + 3) * 68 + r] = t.w;
        }
        __syncthreads();
        float s8[2][4] = {{0.f, 0.f, 0.f, 0.f}, {0.f, 0.f, 0.f, 0.f}};
        for (int d = 0; d < 128; ++d) {
            float2 qv = *(const float2*)&Qt[d][sy * 2];
            float4 kv4 = *(const float4*)&KV[d * 68 + sx * 4];
            s8[0][0] = fmaf(qv.x, kv4.x, s8[0][0]);
            s8[0][1] = fmaf(qv.x, kv4.y, s8[0][1]);
            s8[0][2] = fmaf(qv.x, kv4.z, s8[0][2]);
            s8[0][3] = fmaf(qv.x, kv4.w, s8[0][3]);
            s8[1][0] = fmaf(qv.y, kv4.x, s8[1][0]);
            s8[1][1] = fmaf(qv.y, kv4.y, s8[1][1]);
            s8[1][2] = fmaf(qv.y, kv4.z, s8[1][2]);
            s8[1][3] = fmaf(qv.y, kv4.w, s8[1][3]);
        }
#pragma unroll
        for (int i = 0; i < 2; ++i) {
            int gr = r0 + sy * 2 + i;
#pragma unroll
            for (int jj = 0; jj < 4; ++jj) {
                int gj = j0 + sx * 4 + jj;
                float val = s8[i][jj] * scale;
                Ps[sy * 2 + i][sx * 4 + jj] = (gj > gr) ? -INFINITY : val;
            }
        }
        __syncthreads();
        {
            const int c0 = (tid & 7) * 8;
            float sv[8];
            float mx = -INFINITY;
#pragma unroll
            for (int i = 0; i < 8; ++i) { sv[i] = Ps[orow][c0 + i]; mx = fmaxf(mx, sv[i]); }
            mx = fmaxf(mx, __shfl_xor(mx, 1));
            mx = fmaxf(mx, __shfl_xor(mx, 2));
            mx = fmaxf(mx, __shfl_xor(mx, 4));
            float m_new = fmaxf(m_run, mx);
            float corr = expf(m_run - m_new);
            float lsum = 0.f;
#pragma unroll
            for (int i = 0; i < 8; ++i) {
                float p = expf(sv[i] - m_new);
                Ps[orow][c0 + i] = p;
                lsum += p;
            }
            lsum += __shfl_xor(lsum, 1);
            lsum += __shfl_xor(lsum, 2);
            lsum += __shfl_xor(lsum, 4);
            l_run = l_run * corr + lsum;
            m_run = m_new;
#pragma unroll
            for (int u = 0; u < 4; ++u)
#pragma unroll
                for (int i = 0; i < 4; ++i) acc[u][i] *= corr;
        }
        __syncthreads();
#pragma unroll
        for (int i = 0; i < 8; ++i) {
            int flat = tid + 256 * i;
            int r = flat >> 5;
            int d = (flat & 31) << 2;
            float4 t = *(const float4*)(v + (size_t)(j0 + r) * HIDDEN + h * HD + d);
            *(float4*)&KV[r * 136 + d] = t;
        }
        __syncthreads();
        for (int j = 0; j < KT; ++j) {
            float p = Ps[orow][j];
#pragma unroll
            for (int u = 0; u < 4; ++u) {
                float4 vv = *(const float4*)&KV[j * 136 + oc4 + u * 32];
                acc[u][0] = fmaf(p, vv.x, acc[u][0]);
                acc[u][1] = fmaf(p, vv.y, acc[u][1]);
                acc[u][2] = fmaf(p, vv.z, acc[u][2]);
                acc[u][3] = fmaf(p, vv.w, acc[u][3]);
            }
        }
    }

    float inv_l = 1.0f / l_run;
#pragma unroll
    for (int u = 0; u < 4; ++u)
#pragma unroll
        for (int i = 0; i < 4; ++i) acc[u][i] *= inv_l;

    {
        float g = tanhf(gate[h]);
        float sp[PLEN];
        float mp = -INFINITY;
#pragma unroll
        for (int i = 0; i < PLEN; ++i) {
            const float* kpr = kp + (size_t)i * HIDDEN + h * HD;
            float s = 0.f;
            for (int d = 0; d < 128; ++d) s = fmaf(Qt[d][orow], kpr[d], s);
            sp[i] = s * scale;
            mp = fmaxf(mp, sp[i]);
        }
        float ssum = 0.f;
#pragma unroll
        for (int i = 0; i < PLEN; ++i) { sp[i] = expf(sp[i] - mp); ssum += sp[i]; }
        float gs = g / ssum;
#pragma unroll
        for (int i = 0; i < PLEN; ++i) {
            float w = sp[i] * gs;
            const float* vpr = vp + (size_t)i * HIDDEN + h * HD;
#pragma unroll
            for (int u = 0; u < 4; ++u) {
                float4 vv = *(const float4*)(vpr + oc4 + u * 32);
                acc[u][0] = fmaf(w, vv.x, acc[u][0]);
                acc[u][1] = fmaf(w, vv.y, acc[u][1]);
                acc[u][2] = fmaf(w, vv.z, acc[u][2]);
                acc[u][3] = fmaf(w, vv.w, acc[u][3]);
            }
        }
    }

    float* op = out + (size_t)(r0 + orow) * HIDDEN + h * HD;
#pragma unroll
    for (int u = 0; u < 4; ++u)
        *(float4*)(op + oc4 + u * 32) = make_float4(acc[u][0], acc[u][1], acc[u][2], acc[u][3]);
}

extern "C" void kernel_launch(void* const* d_in, const int* in_sizes, int n_in,
                              void* d_out, int out_size, void* d_ws, size_t ws_size,
                              hipStream_t stream)
{
    (void)in_sizes; (void)n_in; (void)out_size;
    const float* hidden  = (const float*)d_in[0];
    const int*   pos     = (const int*)d_in[2];
    const float* Wq      = (const float*)d_in[3];
    const float* Wk      = (const float*)d_in[4];
    const float* Wv      = (const float*)d_in[5];
    const float* Wo      = (const float*)d_in[6];
    const float* adapter = (const float*)d_in[7];
    const float* gate    = (const float*)d_in[8];
    float* out = (float*)d_out;

    float* ws = (float*)d_ws;
    const size_t SH = (size_t)SEQQ * HIDDEN;          // 8,388,608
    const size_t WN = (size_t)HIDDEN * HIDDEN;        // 16,777,216
    const size_t PN = (size_t)128 * HIDDEN;           // padded adapter rows
    float* qb   = ws;
    float* kb   = ws + SH;
    float* vb   = ws + 2 * SH;
    float* kpb  = ws + 3 * SH;
    float* vpb  = kpb + (size_t)PLEN * HIDDEN;
    float* cosT = vpb + (size_t)PLEN * HIDDEN;
    float* sinT = cosT + (size_t)SEQQ * 64;
    ushort_t* Hhi = (ushort_t*)(sinT + (size_t)SEQQ * 64);
    ushort_t* Hlo = Hhi + SH;
    ushort_t* Whi = Hlo + SH;
    ushort_t* Wlo = Whi + WN;
    ushort_t* Phi = Wlo + WN;
    ushort_t* Plo = Phi + PN;
    const size_t need = (size_t)((char*)(Plo + PN) - (char*)d_ws);
    const bool use_mfma = (ws_size >= need);

    rope_table_kernel<<<SEQQ, 64, 0, stream>>>(pos, cosT, sinT);

    dim3 blk(256);
    dim3 gbig(HIDDEN / 128, SEQQ / 128);      // 32 x 16 = 512 blocks
    dim3 gsm(HIDDEN / 128, 1);                // 32 blocks
    const int nH8 = (int)(SH / 8);
    const int nW8 = (int)(WN / 8);

    if (use_mfma) {
        convert_hilo_kernel<<<nH8 / 256, blk, 0, stream>>>(hidden, Hhi, Hlo, nH8);
        convert_pad_kernel<<<(int)(PN / 8 / 256), blk, 0, stream>>>(adapter, Phi, Plo);

        convert_hilo_kernel<<<nW8 / 256, blk, 0, stream>>>(Wq, Whi, Wlo, nW8);
        gemm_mfma_split_kernel<<<gbig, blk, 0, stream>>>(Hhi, Hlo, Whi, Wlo, qb, SEQQ, HIDDEN, HIDDEN, SEQQ);

        convert_hilo_kernel<<<nW8 / 256, blk, 0, stream>>>(Wk, Whi, Wlo, nW8);
        gemm_mfma_split_kernel<<<gbig, blk, 0, stream>>>(Hhi, Hlo, Whi, Wlo, kb, SEQQ, HIDDEN, HIDDEN, SEQQ);
        gemm_mfma_split_kernel<<<gsm, blk, 0, stream>>>(Phi, Plo, Whi, Wlo, kpb, 128, HIDDEN, HIDDEN, PLEN);

        convert_hilo_kernel<<<nW8 / 256, blk, 0, stream>>>(Wv, Whi, Wlo, nW8);
        gemm_mfma_split_kernel<<<gbig, blk, 0, stream>>>(Hhi, Hlo, Whi, Wlo, vb, SEQQ, HIDDEN, HIDDEN, SEQQ);
        gemm_mfma_split_kernel<<<gsm, blk, 0, stream>>>(Phi, Plo, Whi, Wlo, vpb, 128, HIDDEN, HIDDEN, PLEN);
    } else {
        gemm_nt_kernel<<<gbig, blk, 0, stream>>>(hidden, Wq, qb, SEQQ, HIDDEN, HIDDEN);
        gemm_nt_kernel<<<gbig, blk, 0, stream>>>(hidden, Wk, kb, SEQQ, HIDDEN, HIDDEN);
        gemm_nt_kernel<<<gbig, blk, 0, stream>>>(hidden, Wv, vb, SEQQ, HIDDEN, HIDDEN);
        gemm_nt_kernel<<<gsm, blk, 0, stream>>>(adapter, Wk, kpb, PLEN, HIDDEN, HIDDEN);
        gemm_nt_kernel<<<gsm, blk, 0, stream>>>(adapter, Wv, vpb, PLEN, HIDDEN, HIDDEN);
    }

    rope_apply_kernel<<<(SEQQ * 2048) / 256, 256, 0, stream>>>(qb, kb, cosT, sinT);

    attn_kernel<<<dim3(SEQQ / QT, NH), blk, 0, stream>>>(qb, kb, vb, kpb, vpb, gate, qb);

    if (use_mfma) {
        convert_hilo_kernel<<<nH8 / 256, blk, 0, stream>>>(qb, Hhi, Hlo, nH8);
        convert_hilo_kernel<<<nW8 / 256, blk, 0, stream>>>(Wo, Whi, Wlo, nW8);
        gemm_mfma_split_kernel<<<gbig, blk, 0, stream>>>(Hhi, Hlo, Whi, Wlo, out, SEQQ, HIDDEN, HIDDEN, SEQQ);
    } else {
        gemm_nt_kernel<<<gbig, blk, 0, stream>>>(qb, Wo, out, SEQQ, HIDDEN, HIDDEN);
    }
}

// Round 6
// 1445.480 us; speedup vs baseline: 4.2970x; 1.8347x over previous
//
#include <hip/hip_runtime.h>
#include <math.h>

#define HIDDEN 4096
#define NH 32
#define HD 128
#define PLEN 10
#define SEQQ 2048
#define QT 32
#define KT 64

typedef __attribute__((ext_vector_type(8))) short bf16x8;
typedef __attribute__((ext_vector_type(4))) float f32x4;
typedef unsigned short ushort_t;

__device__ inline unsigned short f2bf(float f) {
    unsigned u = __float_as_uint(f);
    u += 0x7FFFu + ((u >> 16) & 1u);     // round-to-nearest-even
    return (unsigned short)(u >> 16);
}
__device__ inline float bf2f(unsigned short h) {
    return __uint_as_float(((unsigned)h) << 16);
}

// async global->LDS, 16 bytes per lane; LDS dest is wave-uniform base + lane*16
#define GLD16(g, l) __builtin_amdgcn_global_load_lds( \
        (const __attribute__((address_space(1))) void*)(g), \
        (__attribute__((address_space(3))) void*)(l), 16, 0, 0)

// ---------------- fp32 -> (bf16 hi, bf16 lo) planes, 8 elems/thread ----------------
__global__ __launch_bounds__(256) void convert_hilo_kernel(
    const float* __restrict__ x, ushort_t* __restrict__ hi,
    ushort_t* __restrict__ lo, int n8)
{
    int idx = blockIdx.x * 256 + threadIdx.x;
    if (idx >= n8) return;
    const float4* xp = (const float4*)x;
    float4 a = xp[idx * 2], b = xp[idx * 2 + 1];
    float v[8] = {a.x, a.y, a.z, a.w, b.x, b.y, b.z, b.w};
    unsigned hu[4], lu[4];
#pragma unroll
    for (int i = 0; i < 4; ++i) {
        unsigned short h0 = f2bf(v[2 * i]);
        unsigned short l0 = f2bf(v[2 * i] - bf2f(h0));
        unsigned short h1 = f2bf(v[2 * i + 1]);
        unsigned short l1 = f2bf(v[2 * i + 1] - bf2f(h1));
        hu[i] = (unsigned)h0 | ((unsigned)h1 << 16);
        lu[i] = (unsigned)l0 | ((unsigned)l1 << 16);
    }
    ((uint4*)hi)[idx] = make_uint4(hu[0], hu[1], hu[2], hu[3]);
    ((uint4*)lo)[idx] = make_uint4(lu[0], lu[1], lu[2], lu[3]);
}

// ---------------- adapter (10x4096) -> zero-padded 128x4096 hi/lo planes ----------------
__global__ __launch_bounds__(256) void convert_pad_kernel(
    const float* __restrict__ src, ushort_t* __restrict__ hi, ushort_t* __restrict__ lo)
{
    int idx = blockIdx.x * 256 + threadIdx.x;   // 65536 chunks of 8 elems
    int row = idx >> 9;                          // 512 chunks per row
    unsigned hu[4], lu[4];
    if (row < PLEN) {
        const float4* xp = (const float4*)src;
        float4 a = xp[idx * 2], b = xp[idx * 2 + 1];
        float v[8] = {a.x, a.y, a.z, a.w, b.x, b.y, b.z, b.w};
#pragma unroll
        for (int i = 0; i < 4; ++i) {
            unsigned short h0 = f2bf(v[2 * i]);
            unsigned short l0 = f2bf(v[2 * i] - bf2f(h0));
            unsigned short h1 = f2bf(v[2 * i + 1]);
            unsigned short l1 = f2bf(v[2 * i + 1] - bf2f(h1));
            hu[i] = (unsigned)h0 | ((unsigned)h1 << 16);
            lu[i] = (unsigned)l0 | ((unsigned)l1 << 16);
        }
    } else {
#pragma unroll
        for (int i = 0; i < 4; ++i) { hu[i] = 0u; lu[i] = 0u; }
    }
    ((uint4*)hi)[idx] = make_uint4(hu[0], hu[1], hu[2], hu[3]);
    ((uint4*)lo)[idx] = make_uint4(lu[0], lu[1], lu[2], lu[3]);
}

// ---------------- split-bf16 MFMA GEMM NT (m97 structure) ----------------
__global__ __launch_bounds__(256) void gemm_mfma_split_kernel(
    const ushort_t* __restrict__ Ahi, const ushort_t* __restrict__ Alo,
    const ushort_t* __restrict__ Bhi, const ushort_t* __restrict__ Blo,
    float* __restrict__ C, int M, int N, int K, int Mstore)
{
    __shared__ short lds[4 * 4096];     // planes: 0 Ahi, 1 Alo, 2 Bhi, 3 Blo; each [128][32]

    const int tid = threadIdx.x;
    const int lane = tid & 63;
    const int wave = tid >> 6;

    const int gx = gridDim.x;
    const int nwg = gx * gridDim.y;
    const int flat = blockIdx.y * gx + blockIdx.x;
    const int cpx = nwg >> 3;
    const int sw = (flat & 7) * cpx + (flat >> 3);
    const int m0 = (sw / gx) * 128;
    const int n0 = (sw % gx) * 128;

    const ushort_t* src = (wave == 0) ? Ahi : (wave == 1) ? Alo : (wave == 2) ? Bhi : Blo;
    const int tb = (wave < 2) ? m0 : n0;
    const int sl_st = ((lane >> 2) & 3) ^ ((lane >> 4) & 3);
    const ushort_t* p0 = src + (size_t)(tb + (lane >> 2)) * K + (((lane & 3) ^ sl_st) << 3);
    short* ldsw = &lds[wave * 4096];

    const int lr = lane & 15;
    const int lq = lane >> 4;
    const int wm = (wave >> 1) * 64;
    const int wn = (wave & 1) * 64;
    const int sl_rd = (lr & 3) ^ ((lr >> 2) & 3);
    const int slot = ((lq ^ sl_rd) << 3);

    f32x4 acc[4][4];
#pragma unroll
    for (int m = 0; m < 4; ++m)
#pragma unroll
        for (int n = 0; n < 4; ++n) acc[m][n] = (f32x4){0.f, 0.f, 0.f, 0.f};

#pragma unroll
    for (int c = 0; c < 8; ++c)
        GLD16(p0 + (size_t)c * 16 * K, ldsw + c * 512);

    const int NK = K >> 5;
    for (int ks = 0; ks < NK; ++ks) {
        __syncthreads();

        bf16x8 ah[4], al[4], bh[4], bl[4];
#pragma unroll
        for (int m = 0; m < 4; ++m) {
            int off = ((wm + m * 16 + lr) << 5) + slot;
            ah[m] = *(const bf16x8*)&lds[off];
            al[m] = *(const bf16x8*)&lds[4096 + off];
        }
#pragma unroll
        for (int n = 0; n < 4; ++n) {
            int off = ((wn + n * 16 + lr) << 5) + slot;
            bh[n] = *(const bf16x8*)&lds[8192 + off];
            bl[n] = *(const bf16x8*)&lds[12288 + off];
        }
#pragma unroll
        for (int m = 0; m < 4; ++m)
#pragma unroll
            for (int n = 0; n < 4; ++n) {
                acc[m][n] = __builtin_amdgcn_mfma_f32_16x16x32_bf16(ah[m], bh[n], acc[m][n], 0, 0, 0);
                acc[m][n] = __builtin_amdgcn_mfma_f32_16x16x32_bf16(ah[m], bl[n], acc[m][n], 0, 0, 0);
                acc[m][n] = __builtin_amdgcn_mfma_f32_16x16x32_bf16(al[m], bh[n], acc[m][n], 0, 0, 0);
            }

        __syncthreads();
        if (ks + 1 < NK) {
            const int k0 = (ks + 1) << 5;
#pragma unroll
            for (int c = 0; c < 8; ++c)
                GLD16(p0 + (size_t)c * 16 * K + k0, ldsw + c * 512);
        }
    }

#pragma unroll
    for (int m = 0; m < 4; ++m) {
        const int row = m0 + wm + m * 16 + lq * 4;
#pragma unroll
        for (int n = 0; n < 4; ++n) {
            const int col = n0 + wn + n * 16 + lr;
#pragma unroll
            for (int j = 0; j < 4; ++j)
                if (row + j < Mstore)
                    C[(size_t)(row + j) * N + col] = acc[m][n][j];
        }
    }
}

// ---------------- RoPE cos/sin tables ----------------
__global__ void rope_table_kernel(const int* __restrict__ pos,
                                  float* __restrict__ cosT, float* __restrict__ sinT)
{
    int s = blockIdx.x;
    int j = threadIdx.x;               // 0..63
    float p = (float)pos[s];
    float expnt = (2.0f * (float)j) * (1.0f / 128.0f);
    float inv_freq = powf(10000.0f, -expnt);
    float f = p * inv_freq;
    cosT[s * 64 + j] = cosf(f);
    sinT[s * 64 + j] = sinf(f);
}

// ---------------- RoPE apply -> bf16 hi/lo planes for Q and K ----------------
__global__ void rope_bf16_kernel(const float* __restrict__ q, const float* __restrict__ k,
                                 const float* __restrict__ cosT, const float* __restrict__ sinT,
                                 ushort_t* __restrict__ qhi, ushort_t* __restrict__ qlo,
                                 ushort_t* __restrict__ khi, ushort_t* __restrict__ klo)
{
    int idx = blockIdx.x * 256 + threadIdx.x;
    int s = idx >> 11;
    int rem = idx & 2047;
    int h = rem >> 6;
    int d = rem & 63;
    float c = cosT[s * 64 + d], sn = sinT[s * 64 + d];
    size_t base = (size_t)s * HIDDEN + h * HD + d;
    float a = q[base], b = q[base + 64];
    float r0 = a * c - b * sn;
    float r1 = b * c + a * sn;
    unsigned short h0 = f2bf(r0);
    qhi[base] = h0;       qlo[base] = f2bf(r0 - bf2f(h0));
    h0 = f2bf(r1);
    qhi[base + 64] = h0;  qlo[base + 64] = f2bf(r1 - bf2f(h0));
    a = k[base]; b = k[base + 64];
    r0 = a * c - b * sn;
    r1 = b * c + a * sn;
    h0 = f2bf(r0);
    khi[base] = h0;       klo[base] = f2bf(r0 - bf2f(h0));
    h0 = f2bf(r1);
    khi[base + 64] = h0;  klo[base + 64] = f2bf(r1 - bf2f(h0));
}

// ---------------- V [s][h*128+d] fp32 -> Vt hi/lo planes [h][d][s] bf16 ----------------
__global__ __launch_bounds__(256) void vtranspose_kernel(
    const float* __restrict__ v, ushort_t* __restrict__ vthi, ushort_t* __restrict__ vtlo)
{
    __shared__ float Vs[64][129];
    const int h = blockIdx.y;
    const int s0 = blockIdx.x * 64;
    const int tid = threadIdx.x;
#pragma unroll
    for (int i = 0; i < 8; ++i) {
        int flat = tid + 256 * i;          // 0..2047
        int r = flat >> 5;
        int c4 = (flat & 31) * 4;
        float4 t = *(const float4*)(v + (size_t)(s0 + r) * HIDDEN + h * HD + c4);
        Vs[r][c4] = t.x; Vs[r][c4 + 1] = t.y; Vs[r][c4 + 2] = t.z; Vs[r][c4 + 3] = t.w;
    }
    __syncthreads();
#pragma unroll
    for (int pass = 0; pass < 4; ++pass) {
        int d = pass * 32 + (tid >> 3);
        int sb = (tid & 7) * 8;
        unsigned hu[4], lu[4];
#pragma unroll
        for (int e = 0; e < 4; ++e) {
            float v0 = Vs[sb + e * 2][d], v1 = Vs[sb + e * 2 + 1][d];
            unsigned short h0 = f2bf(v0), l0 = f2bf(v0 - bf2f(h0));
            unsigned short h1 = f2bf(v1), l1 = f2bf(v1 - bf2f(h1));
            hu[e] = (unsigned)h0 | ((unsigned)h1 << 16);
            lu[e] = (unsigned)l0 | ((unsigned)l1 << 16);
        }
        size_t off = ((size_t)h * HD + d) * SEQQ + s0 + sb;
        *(uint4*)(vthi + off) = make_uint4(hu[0], hu[1], hu[2], hu[3]);
        *(uint4*)(vtlo + off) = make_uint4(lu[0], lu[1], lu[2], lu[3]);
    }
}

// ---------------- MFMA flash attention, split-bf16, causal + gated prefix ----------------
// grid (NH, SEQQ/64), 256 threads = 4 waves; wave w owns q-rows q0+w*16..+15.
__global__ __launch_bounds__(256) void attn_mfma_kernel(
    const ushort_t* __restrict__ Qhi, const ushort_t* __restrict__ Qlo,
    const ushort_t* __restrict__ Khi, const ushort_t* __restrict__ Klo,
    const ushort_t* __restrict__ Vthi, const ushort_t* __restrict__ Vtlo,
    const float* __restrict__ kp, const float* __restrict__ vp,
    const float* __restrict__ gate, float* __restrict__ out)
{
    __shared__ short KVs[2][64 * 128];   // 32KB: K tiles [j][128] or Vt tiles [d][64]
    __shared__ float Ps[4][16][68];      // P transpose buffer per wave
    __shared__ float Pp[4][16][12];      // gated prefix probs per wave

    const int h = blockIdx.x;
    const int q0 = blockIdx.y * 64;
    const int tid = threadIdx.x;
    const int wave = tid >> 6;
    const int lane = tid & 63;
    const int lr = lane & 15;
    const int lq = lane >> 4;
    const float scale = 0.088388347648318447f;   // 1/sqrt(128)

    // ---- Q fragments (a-frag: row=lr, k=lq*8+e within 32-chunk c) ----
    const int qrow = q0 + wave * 16 + lr;
    bf16x8 qh[4], ql[4];
#pragma unroll
    for (int c = 0; c < 4; ++c) {
        size_t o = (size_t)qrow * HIDDEN + h * HD + c * 32 + lq * 8;
        qh[c] = *(const bf16x8*)(Qhi + o);
        ql[c] = *(const bf16x8*)(Qlo + o);
    }

    f32x4 accO[8];
#pragma unroll
    for (int n = 0; n < 8; ++n) accO[n] = (f32x4){0.f, 0.f, 0.f, 0.f};
    float m_run[4] = {-INFINITY, -INFINITY, -INFINITY, -INFINITY};
    float l_run[4] = {0.f, 0.f, 0.f, 0.f};

    const int ntiles = blockIdx.y + 1;
    for (int t = 0; t < ntiles; ++t) {
        const int j0 = t * 64;
        __syncthreads();                 // prev tile's PV reads done

        // ---- stage K tile (hi+lo), chunk-swizzled source, linear LDS ----
        {
            const ushort_t* ksrc = (wave >> 1) ? Klo : Khi;
            const int rbase = (wave & 1) * 32;
            short* kdst = &KVs[wave >> 1][rbase * 128];
            const int rl = lane >> 4;    // 0..3
            const int ch = lane & 15;
#pragma unroll
            for (int ii = 0; ii < 8; ++ii) {
                int r = rbase + ii * 4 + rl;
                int chs = ch ^ (r & 7);
                const ushort_t* g = ksrc + (size_t)(j0 + r) * HIDDEN + h * HD + chs * 8;
                GLD16(g, kdst + ii * 512);
            }
        }
        __syncthreads();                 // K resident

        // ---- S = Q K^T (split: hh + hl + lh), 16x64 per wave ----
        f32x4 sacc[4];
#pragma unroll
        for (int n = 0; n < 4; ++n) sacc[n] = (f32x4){0.f, 0.f, 0.f, 0.f};
#pragma unroll
        for (int c = 0; c < 4; ++c) {
#pragma unroll
            for (int n = 0; n < 4; ++n) {
                int row = n * 16 + lr;
                int chs = (4 * c + lq) ^ (lr & 7);
                bf16x8 kh = *(const bf16x8*)&KVs[0][row * 128 + chs * 8];
                bf16x8 kl = *(const bf16x8*)&KVs[1][row * 128 + chs * 8];
                sacc[n] = __builtin_amdgcn_mfma_f32_16x16x32_bf16(qh[c], kh, sacc[n], 0, 0, 0);
                sacc[n] = __builtin_amdgcn_mfma_f32_16x16x32_bf16(qh[c], kl, sacc[n], 0, 0, 0);
                sacc[n] = __builtin_amdgcn_mfma_f32_16x16x32_bf16(ql[c], kh, sacc[n], 0, 0, 0);
            }
        }

        // ---- scale + causal mask + online softmax (C rows = lq*4+j) ----
#pragma unroll
        for (int j = 0; j < 4; ++j) {
            const int grow = q0 + wave * 16 + lq * 4 + j;
#pragma unroll
            for (int n = 0; n < 4; ++n) {
                int gcol = j0 + n * 16 + lr;
                float val = sacc[n][j] * scale;
                sacc[n][j] = (gcol > grow) ? -INFINITY : val;
            }
            float mx = fmaxf(fmaxf(sacc[0][j], sacc[1][j]), fmaxf(sacc[2][j], sacc[3][j]));
            mx = fmaxf(mx, __shfl_xor(mx, 1));
            mx = fmaxf(mx, __shfl_xor(mx, 2));
            mx = fmaxf(mx, __shfl_xor(mx, 4));
            mx = fmaxf(mx, __shfl_xor(mx, 8));
            float mn = fmaxf(m_run[j], mx);
            float corr = expf(m_run[j] - mn);   // 0 on first tile
            m_run[j] = mn;
            float ls = 0.f;
#pragma unroll
            for (int n = 0; n < 4; ++n) {
                float p = expf(sacc[n][j] - mn);
                Ps[wave][lq * 4 + j][n * 16 + lr] = p;
                ls += p;
            }
            ls += __shfl_xor(ls, 1);
            ls += __shfl_xor(ls, 2);
            ls += __shfl_xor(ls, 4);
            ls += __shfl_xor(ls, 8);
            l_run[j] = l_run[j] * corr + ls;
#pragma unroll
            for (int n = 0; n < 8; ++n) accO[n][j] *= corr;
        }

        __syncthreads();                 // all waves done reading K LDS

        // ---- stage Vt tile (hi+lo) [128 d][64 j], chunk-swizzled ----
        {
            const ushort_t* vsrc = (wave >> 1) ? Vtlo : Vthi;
            const int dbase = (wave & 1) * 64;
            short* vdst = &KVs[wave >> 1][dbase * 64];
            const int dl = lane >> 3;    // 0..7
            const int vch = lane & 7;
#pragma unroll
            for (int ii = 0; ii < 8; ++ii) {
                int d = dbase + ii * 8 + dl;
                int chs = vch ^ (d & 7);
                const ushort_t* g = vsrc + ((size_t)h * HD + d) * SEQQ + j0 + chs * 8;
                GLD16(g, vdst + ii * 512);
            }
        }
        __syncthreads();                 // Vt resident

        // ---- PV: out += P V (split) ----
#pragma unroll
        for (int jc = 0; jc < 2; ++jc) {
            float pv[8];
            *(float4*)&pv[0] = *(const float4*)&Ps[wave][lr][jc * 32 + lq * 8];
            *(float4*)&pv[4] = *(const float4*)&Ps[wave][lr][jc * 32 + lq * 8 + 4];
            bf16x8 pa_h, pa_l;
#pragma unroll
            for (int e = 0; e < 8; ++e) {
                unsigned short ph = f2bf(pv[e]);
                pa_h[e] = (short)ph;
                pa_l[e] = (short)f2bf(pv[e] - bf2f(ph));
            }
#pragma unroll
            for (int n = 0; n < 8; ++n) {
                int row = n * 16 + lr;
                int chv = (jc * 4 + lq) ^ (lr & 7);
                bf16x8 vh = *(const bf16x8*)&KVs[0][row * 64 + chv * 8];
                bf16x8 vl = *(const bf16x8*)&KVs[1][row * 64 + chv * 8];
                accO[n] = __builtin_amdgcn_mfma_f32_16x16x32_bf16(pa_h, vh, accO[n], 0, 0, 0);
                accO[n] = __builtin_amdgcn_mfma_f32_16x16x32_bf16(pa_h, vl, accO[n], 0, 0, 0);
                accO[n] = __builtin_amdgcn_mfma_f32_16x16x32_bf16(pa_l, vh, accO[n], 0, 0, 0);
            }
        }
    }

    // ---- normalize token part ----
    float inv_l[4];
#pragma unroll
    for (int j = 0; j < 4; ++j) inv_l[j] = 1.0f / l_run[j];
#pragma unroll
    for (int n = 0; n < 8; ++n)
#pragma unroll
        for (int j = 0; j < 4; ++j) accO[n][j] *= inv_l[j];

    // ---- gated prefix: scores from (hi+lo) Q rows (a-frag row = lr) ----
    {
        float g = tanhf(gate[h]);
        float sp[PLEN];
        float mp = -INFINITY;
#pragma unroll
        for (int i = 0; i < PLEN; ++i) {
            const float* kpr = kp + (size_t)i * HIDDEN + h * HD;
            float s = 0.f;
#pragma unroll
            for (int c = 0; c < 4; ++c)
#pragma unroll
                for (int e = 0; e < 8; ++e) {
                    float qv = bf2f((unsigned short)qh[c][e]) + bf2f((unsigned short)ql[c][e]);
                    s = fmaf(qv, kpr[c * 32 + lq * 8 + e], s);
                }
            s += __shfl_xor(s, 16);
            s += __shfl_xor(s, 32);
            sp[i] = s * scale;
            mp = fmaxf(mp, sp[i]);
        }
        float ssum = 0.f;
#pragma unroll
        for (int i = 0; i < PLEN; ++i) { sp[i] = expf(sp[i] - mp); ssum += sp[i]; }
        float gs = g / ssum;
        if (lq == 0) {
#pragma unroll
            for (int i = 0; i < PLEN; ++i) Pp[wave][lr][i] = sp[i] * gs;
        }
        // prefix PV accumulate (C rows = lq*4+j, cols d = n*16+lr)
#pragma unroll
        for (int i = 0; i < PLEN; ++i) {
            float vv[8];
#pragma unroll
            for (int n = 0; n < 8; ++n)
                vv[n] = vp[(size_t)i * HIDDEN + h * HD + n * 16 + lr];
#pragma unroll
            for (int j = 0; j < 4; ++j) {
                float w = Pp[wave][lq * 4 + j][i];
#pragma unroll
                for (int n = 0; n < 8; ++n) accO[n][j] = fmaf(w, vv[n], accO[n][j]);
            }
        }
    }

    // ---- store fp32 output ----
#pragma unroll
    for (int n = 0; n < 8; ++n)
#pragma unroll
        for (int j = 0; j < 4; ++j)
            out[(size_t)(q0 + wave * 16 + lq * 4 + j) * HIDDEN + h * HD + n * 16 + lr] = accO[n][j];
}

// ---------------- fp32 GEMM NT (ws-too-small fallback only) ----------------
__global__ __launch_bounds__(256) void gemm_nt_kernel(
    const float* __restrict__ A, const float* __restrict__ B, float* __restrict__ C,
    int M, int N, int K)
{
    __shared__ float As[8][132];
    __shared__ float Bs[8][132];
    const int tid = threadIdx.x;
    const int tx = tid & 15, ty = tid >> 4;
    const int m0 = blockIdx.y * 128, n0 = blockIdx.x * 128;
    const int lr = tid >> 1;
    const int lk = (tid & 1) * 4;
    const bool aval = (m0 + lr) < M;
    const float* Ap = A + (size_t)(m0 + lr) * K + lk;
    const float* Bp = B + (size_t)(n0 + lr) * K + lk;

    float acc[8][8];
#pragma unroll
    for (int i = 0; i < 8; ++i)
#pragma unroll
        for (int j = 0; j < 8; ++j) acc[i][j] = 0.0f;

    for (int k0 = 0; k0 < K; k0 += 8) {
        float4 a4 = make_float4(0.f, 0.f, 0.f, 0.f);
        if (aval) a4 = *(const float4*)(Ap + k0);
        float4 b4 = *(const float4*)(Bp + k0);
        __syncthreads();
        As[lk + 0][lr] = a4.x; As[lk + 1][lr] = a4.y; As[lk + 2][lr] = a4.z; As[lk + 3][lr] = a4.w;
        Bs[lk + 0][lr] = b4.x; Bs[lk + 1][lr] = b4.y; Bs[lk + 2][lr] = b4.z; Bs[lk + 3][lr] = b4.w;
        __syncthreads();
#pragma unroll
        for (int kk = 0; kk < 8; ++kk) {
            float4 a0 = *(const float4*)&As[kk][ty * 8];
            float4 a1 = *(const float4*)&As[kk][ty * 8 + 4];
            float4 b0 = *(const float4*)&Bs[kk][tx * 8];
            float4 b1 = *(const float4*)&Bs[kk][tx * 8 + 4];
            float a[8] = {a0.x, a0.y, a0.z, a0.w, a1.x, a1.y, a1.z, a1.w};
            float b[8] = {b0.x, b0.y, b0.z, b0.w, b1.x, b1.y, b1.z, b1.w};
#pragma unroll
            for (int i = 0; i < 8; ++i)
#pragma unroll
                for (int j = 0; j < 8; ++j)
                    acc[i][j] = fmaf(a[i], b[j], acc[i][j]);
        }
    }
#pragma unroll
    for (int i = 0; i < 8; ++i) {
        int row = m0 + ty * 8 + i;
        if (row < M) {
            float* Cp = C + (size_t)row * N + n0 + tx * 8;
            *(float4*)Cp       = make_float4(acc[i][0], acc[i][1], acc[i][2], acc[i][3]);
            *(float4*)(Cp + 4) = make_float4(acc[i][4], acc[i][5], acc[i][6], acc[i][7]);
        }
    }
}

// ---------------- RoPE apply in place (fallback path) ----------------
__global__ void rope_apply_kernel(float* __restrict__ q, float* __restrict__ k,
                                  const float* __restrict__ cosT, const float* __restrict__ sinT)
{
    int idx = blockIdx.x * 256 + threadIdx.x;
    int s = idx >> 11;
    int rem = idx & 2047;
    int h = rem >> 6;
    int d = rem & 63;
    float c = cosT[s * 64 + d], sn = sinT[s * 64 + d];
    size_t base = (size_t)s * HIDDEN + h * HD + d;
    float a = q[base], b = q[base + 64];
    q[base]      = a * c - b * sn;
    q[base + 64] = b * c + a * sn;
    a = k[base]; b = k[base + 64];
    k[base]      = a * c - b * sn;
    k[base + 64] = b * c + a * sn;
}

// ---------------- fp32 fused attention (fallback path) ----------------
__global__ __launch_bounds__(256) void attn_kernel(
    const float* __restrict__ q, const float* __restrict__ k, const float* __restrict__ v,
    const float* __restrict__ kp, const float* __restrict__ vp,
    const float* __restrict__ gate, float* __restrict__ out)
{
    __shared__ float Qt[128][36];
    __shared__ float KV[128 * 68];
    __shared__ float Psh[QT][68];

    const int h = blockIdx.y;
    const int r0 = blockIdx.x * QT;
    const int tid = threadIdx.x;
    const int orow = tid >> 3;
    const int oc4 = (tid & 7) * 4;
    const int sy = tid >> 4;
    const int sx = tid & 15;
    const float scale = 0.088388347648318447f;

#pragma unroll
    for (int i = 0; i < 4; ++i) {
        int flat = tid + 256 * i;
        int r = flat >> 5;
        int d = (flat & 31) << 2;
        float4 t = *(const float4*)(q + (size_t)(r0 + r) * HIDDEN + h * HD + d);
        Qt[d + 0][r] = t.x; Qt[d + 1][r] = t.y; Qt[d + 2][r] = t.z; Qt[d + 3][r] = t.w;
    }

    float acc[4][4];
#pragma unroll
    for (int u = 0; u < 4; ++u)
#pragma unroll
        for (int i = 0; i < 4; ++i) acc[u][i] = 0.0f;
    float m_run = -INFINITY, l_run = 0.0f;

    const int jb_max = (r0 + QT - 1) >> 6;
    for (int jb = 0; jb <= jb_max; ++jb) {
        const int j0 = jb * KT;
        __syncthreads();
#pragma unroll
        for (int i = 0; i < 8; ++i) {
            int flat = tid + 256 * i;
            int r = flat >> 5;
            int d = (flat & 31) << 2;
            float4 t = *(const float4*)(k + (size_t)(j0 + r) * HIDDEN + h * HD + d);
            KV[(d + 0) * 68 + r] = t.x; KV[(d + 1) * 68 + r] = t.y;
            KV[(d + 2) * 68 + r] = t.z; KV[(d + 3) * 68 + r] = t.w;
        }
        __syncthreads();
        float s8[2][4] = {{0.f, 0.f, 0.f, 0.f}, {0.f, 0.f, 0.f, 0.f}};
        for (int d = 0; d < 128; ++d) {
            float2 qv = *(const float2*)&Qt[d][sy * 2];
            float4 kv4 = *(const float4*)&KV[d * 68 + sx * 4];
            s8[0][0] = fmaf(qv.x, kv4.x, s8[0][0]);
            s8[0][1] = fmaf(qv.x, kv4.y, s8[0][1]);
            s8[0][2] = fmaf(qv.x, kv4.z, s8[0][2]);
            s8[0][3] = fmaf(qv.x, kv4.w, s8[0][3]);
            s8[1][0] = fmaf(qv.y, kv4.x, s8[1][0]);
            s8[1][1] = fmaf(qv.y, kv4.y, s8[1][1]);
            s8[1][2] = fmaf(qv.y, kv4.z, s8[1][2]);
            s8[1][3] = fmaf(qv.y, kv4.w, s8[1][3]);
        }
#pragma unroll
        for (int i = 0; i < 2; ++i) {
            int gr = r0 + sy * 2 + i;
#pragma unroll
            for (int jj = 0; jj < 4; ++jj) {
                int gj = j0 + sx * 4 + jj;
                float val = s8[i][jj] * scale;
                Psh[sy * 2 + i][sx * 4 + jj] = (gj > gr) ? -INFINITY : val;
            }
        }
        __syncthreads();
        {
            const int c0 = (tid & 7) * 8;
            float sv[8];
            float mx = -INFINITY;
#pragma unroll
            for (int i = 0; i < 8; ++i) { sv[i] = Psh[orow][c0 + i]; mx = fmaxf(mx, sv[i]); }
            mx = fmaxf(mx, __shfl_xor(mx, 1));
            mx = fmaxf(mx, __shfl_xor(mx, 2));
            mx = fmaxf(mx, __shfl_xor(mx, 4));
            float m_new = fmaxf(m_run, mx);
            float corr = expf(m_run - m_new);
            float lsum = 0.f;
#pragma unroll
            for (int i = 0; i < 8; ++i) {
                float p = expf(sv[i] - m_new);
                Psh[orow][c0 + i] = p;
                lsum += p;
            }
            lsum += __shfl_xor(lsum, 1);
            lsum += __shfl_xor(lsum, 2);
            lsum += __shfl_xor(lsum, 4);
            l_run = l_run * corr + lsum;
            m_run = m_new;
#pragma unroll
            for (int u = 0; u < 4; ++u)
#pragma unroll
                for (int i = 0; i < 4; ++i) acc[u][i] *= corr;
        }
        __syncthreads();
#pragma unroll
        for (int i = 0; i < 8; ++i) {
            int flat = tid + 256 * i;
            int r = flat >> 5;
            int d = (flat & 31) << 2;
            float4 t = *(const float4*)(v + (size_t)(j0 + r) * HIDDEN + h * HD + d);
            *(float4*)&KV[r * 136 + d] = t;
        }
        __syncthreads();
        for (int j = 0; j < KT; ++j) {
            float p = Psh[orow][j];
#pragma unroll
            for (int u = 0; u < 4; ++u) {
                float4 vv = *(const float4*)&KV[j * 136 + oc4 + u * 32];
                acc[u][0] = fmaf(p, vv.x, acc[u][0]);
                acc[u][1] = fmaf(p, vv.y, acc[u][1]);
                acc[u][2] = fmaf(p, vv.z, acc[u][2]);
                acc[u][3] = fmaf(p, vv.w, acc[u][3]);
            }
        }
    }

    float inv_l = 1.0f / l_run;
#pragma unroll
    for (int u = 0; u < 4; ++u)
#pragma unroll
        for (int i = 0; i < 4; ++i) acc[u][i] *= inv_l;

    {
        float g = tanhf(gate[h]);
        float sp[PLEN];
        float mp = -INFINITY;
#pragma unroll
        for (int i = 0; i < PLEN; ++i) {
            const float* kpr = kp + (size_t)i * HIDDEN + h * HD;
            float s = 0.f;
            for (int d = 0; d < 128; ++d) s = fmaf(Qt[d][orow], kpr[d], s);
            sp[i] = s * scale;
            mp = fmaxf(mp, sp[i]);
        }
        float ssum = 0.f;
#pragma unroll
        for (int i = 0; i < PLEN; ++i) { sp[i] = expf(sp[i] - mp); ssum += sp[i]; }
        float gs = g / ssum;
#pragma unroll
        for (int i = 0; i < PLEN; ++i) {
            float w = sp[i] * gs;
            const float* vpr = vp + (size_t)i * HIDDEN + h * HD;
#pragma unroll
            for (int u = 0; u < 4; ++u) {
                float4 vv = *(const float4*)(vpr + oc4 + u * 32);
                acc[u][0] = fmaf(w, vv.x, acc[u][0]);
                acc[u][1] = fmaf(w, vv.y, acc[u][1]);
                acc[u][2] = fmaf(w, vv.z, acc[u][2]);
                acc[u][3] = fmaf(w, vv.w, acc[u][3]);
            }
        }
    }

    float* op = out + (size_t)(r0 + orow) * HIDDEN + h * HD;
#pragma unroll
    for (int u = 0; u < 4; ++u)
        *(float4*)(op + oc4 + u * 32) = make_float4(acc[u][0], acc[u][1], acc[u][2], acc[u][3]);
}

extern "C" void kernel_launch(void* const* d_in, const int* in_sizes, int n_in,
                              void* d_out, int out_size, void* d_ws, size_t ws_size,
                              hipStream_t stream)
{
    (void)in_sizes; (void)n_in; (void)out_size;
    const float* hidden  = (const float*)d_in[0];
    const int*   pos     = (const int*)d_in[2];
    const float* Wq      = (const float*)d_in[3];
    const float* Wk      = (const float*)d_in[4];
    const float* Wv      = (const float*)d_in[5];
    const float* Wo      = (const float*)d_in[6];
    const float* adapter = (const float*)d_in[7];
    const float* gate    = (const float*)d_in[8];
    float* out = (float*)d_out;

    float* ws = (float*)d_ws;
    const size_t SH = (size_t)SEQQ * HIDDEN;          // 8,388,608
    const size_t WN = (size_t)HIDDEN * HIDDEN;        // 16,777,216
    const size_t PN = (size_t)128 * HIDDEN;
    float* qb   = ws;
    float* kb   = ws + SH;
    float* vb   = ws + 2 * SH;
    float* kpb  = ws + 3 * SH;
    float* vpb  = kpb + (size_t)PLEN * HIDDEN;
    float* cosT = vpb + (size_t)PLEN * HIDDEN;
    float* sinT = cosT + (size_t)SEQQ * 64;
    ushort_t* Hhi = (ushort_t*)(sinT + (size_t)SEQQ * 64);
    ushort_t* Hlo = Hhi + SH;
    ushort_t* Whi = Hlo + SH;
    ushort_t* Wlo = Whi + WN;
    ushort_t* Phi = Wlo + WN;
    ushort_t* Plo = Phi + PN;
    const size_t need = (size_t)((char*)(Plo + PN) - (char*)d_ws);
    const bool use_mfma = (ws_size >= need);

    // overlays (mfma path): after last weight GEMM, W planes hold Q/K bf16; H planes hold Vt
    ushort_t* Qhi = Whi;
    ushort_t* Qlo = Whi + SH;
    ushort_t* KhiP = Wlo;
    ushort_t* KloP = Wlo + SH;
    ushort_t* VthiP = Hhi;
    ushort_t* VtloP = Hlo;

    rope_table_kernel<<<SEQQ, 64, 0, stream>>>(pos, cosT, sinT);

    dim3 blk(256);
    dim3 gbig(HIDDEN / 128, SEQQ / 128);
    dim3 gsm(HIDDEN / 128, 1);
    const int nH8 = (int)(SH / 8);
    const int nW8 = (int)(WN / 8);

    if (use_mfma) {
        convert_hilo_kernel<<<nH8 / 256, blk, 0, stream>>>(hidden, Hhi, Hlo, nH8);
        convert_pad_kernel<<<(int)(PN / 8 / 256), blk, 0, stream>>>(adapter, Phi, Plo);

        convert_hilo_kernel<<<nW8 / 256, blk, 0, stream>>>(Wq, Whi, Wlo, nW8);
        gemm_mfma_split_kernel<<<gbig, blk, 0, stream>>>(Hhi, Hlo, Whi, Wlo, qb, SEQQ, HIDDEN, HIDDEN, SEQQ);

        convert_hilo_kernel<<<nW8 / 256, blk, 0, stream>>>(Wk, Whi, Wlo, nW8);
        gemm_mfma_split_kernel<<<gbig, blk, 0, stream>>>(Hhi, Hlo, Whi, Wlo, kb, SEQQ, HIDDEN, HIDDEN, SEQQ);
        gemm_mfma_split_kernel<<<gsm, blk, 0, stream>>>(Phi, Plo, Whi, Wlo, kpb, 128, HIDDEN, HIDDEN, PLEN);

        convert_hilo_kernel<<<nW8 / 256, blk, 0, stream>>>(Wv, Whi, Wlo, nW8);
        gemm_mfma_split_kernel<<<gbig, blk, 0, stream>>>(Hhi, Hlo, Whi, Wlo, vb, SEQQ, HIDDEN, HIDDEN, SEQQ);
        gemm_mfma_split_kernel<<<gsm, blk, 0, stream>>>(Phi, Plo, Whi, Wlo, vpb, 128, HIDDEN, HIDDEN, PLEN);

        // W planes now dead -> write Q/K bf16 planes; H planes dead -> Vt planes
        rope_bf16_kernel<<<(SEQQ * 2048) / 256, blk, 0, stream>>>(qb, kb, cosT, sinT,
                                                                  Qhi, Qlo, KhiP, KloP);
        vtranspose_kernel<<<dim3(SEQQ / 64, NH), blk, 0, stream>>>(vb, VthiP, VtloP);

        attn_mfma_kernel<<<dim3(NH, SEQQ / 64), blk, 0, stream>>>(
            Qhi, Qlo, KhiP, KloP, VthiP, VtloP, kpb, vpb, gate, qb);

        convert_hilo_kernel<<<nH8 / 256, blk, 0, stream>>>(qb, Hhi, Hlo, nH8);
        convert_hilo_kernel<<<nW8 / 256, blk, 0, stream>>>(Wo, Whi, Wlo, nW8);
        gemm_mfma_split_kernel<<<gbig, blk, 0, stream>>>(Hhi, Hlo, Whi, Wlo, out, SEQQ, HIDDEN, HIDDEN, SEQQ);
    } else {
        gemm_nt_kernel<<<gbig, blk, 0, stream>>>(hidden, Wq, qb, SEQQ, HIDDEN, HIDDEN);
        gemm_nt_kernel<<<gbig, blk, 0, stream>>>(hidden, Wk, kb, SEQQ, HIDDEN, HIDDEN);
        gemm_nt_kernel<<<gbig, blk, 0, stream>>>(hidden, Wv, vb, SEQQ, HIDDEN, HIDDEN);
        gemm_nt_kernel<<<gsm, blk, 0, stream>>>(adapter, Wk, kpb, PLEN, HIDDEN, HIDDEN);
        gemm_nt_kernel<<<gsm, blk, 0, stream>>>(adapter, Wv, vpb, PLEN, HIDDEN, HIDDEN);
        rope_apply_kernel<<<(SEQQ * 2048) / 256, 256, 0, stream>>>(qb, kb, cosT, sinT);
        attn_kernel<<<dim3(SEQQ / QT, NH), blk, 0, stream>>>(qb, kb, vb, kpb, vpb, gate, qb);
        gemm_nt_kernel<<<gbig, blk, 0, stream>>>(qb, Wo, out, SEQQ, HIDDEN, HIDDEN);
    }
}

// Round 7
// 882.815 us; speedup vs baseline: 7.0358x; 1.6374x over previous
//
#include <hip/hip_runtime.h>
#include <math.h>

#define HIDDEN 4096
#define NH 32
#define HD 128
#define PLEN 10
#define SEQQ 2048
#define QT 32
#define KT 64

typedef __attribute__((ext_vector_type(8))) _Float16 f16x8;
typedef __attribute__((ext_vector_type(4))) float f32x4;

// async global->LDS, 16 bytes per lane; LDS dest is wave-uniform base + lane*16
#define GLD16(g, l) __builtin_amdgcn_global_load_lds( \
        (const __attribute__((address_space(1))) void*)(g), \
        (__attribute__((address_space(3))) void*)(l), 16, 0, 0)

// ---------------- fp32 -> fp16 plane, 8 elems/thread ----------------
__global__ __launch_bounds__(256) void cvt_f16_kernel(
    const float* __restrict__ x, _Float16* __restrict__ y, int n8)
{
    int idx = blockIdx.x * 256 + threadIdx.x;
    if (idx >= n8) return;
    const float4* xp = (const float4*)x;
    float4 a = xp[idx * 2], b = xp[idx * 2 + 1];
    f16x8 o;
    o[0] = (_Float16)a.x; o[1] = (_Float16)a.y; o[2] = (_Float16)a.z; o[3] = (_Float16)a.w;
    o[4] = (_Float16)b.x; o[5] = (_Float16)b.y; o[6] = (_Float16)b.z; o[7] = (_Float16)b.w;
    *(f16x8*)(y + (size_t)idx * 8) = o;
}

// ---------------- adapter (10x4096) -> zero-padded 128x4096 fp16 ----------------
__global__ __launch_bounds__(256) void cvt_pad_f16_kernel(
    const float* __restrict__ src, _Float16* __restrict__ y)
{
    int idx = blockIdx.x * 256 + threadIdx.x;   // 65536 chunks of 8 elems
    int row = idx >> 9;                          // 512 chunks per row
    f16x8 o;
    if (row < PLEN) {
        const float4* xp = (const float4*)src;
        float4 a = xp[idx * 2], b = xp[idx * 2 + 1];
        o[0] = (_Float16)a.x; o[1] = (_Float16)a.y; o[2] = (_Float16)a.z; o[3] = (_Float16)a.w;
        o[4] = (_Float16)b.x; o[5] = (_Float16)b.y; o[6] = (_Float16)b.z; o[7] = (_Float16)b.w;
    } else {
#pragma unroll
        for (int i = 0; i < 8; ++i) o[i] = (_Float16)0.0f;
    }
    *(f16x8*)(y + (size_t)idx * 8) = o;
}

// ---------------- fp16 MFMA GEMM NT (m97 structure): C = A * B^T ----------------
// 128x128 tile, BK=32, 256 threads = 4 waves. global_load_lds staging,
// XOR slot swizzle (pre-swizzled global src + swizzled ds_read).
__global__ __launch_bounds__(256) void gemm_f16_kernel(
    const _Float16* __restrict__ A, const _Float16* __restrict__ B,
    float* __restrict__ C, int N, int K, int Mstore)
{
    __shared__ _Float16 lds[2 * 4096];   // plane A [128][32], plane B [128][32]

    const int tid = threadIdx.x;
    const int lane = tid & 63;
    const int wave = tid >> 6;

    // XCD-aware bijective swizzle (nwg % 8 == 0 for our grids)
    const int gx = gridDim.x;
    const int nwg = gx * gridDim.y;
    const int flat = blockIdx.y * gx + blockIdx.x;
    const int cpx = nwg >> 3;
    const int sw = (flat & 7) * cpx + (flat >> 3);
    const int m0 = (sw / gx) * 128;
    const int n0 = (sw % gx) * 128;

    // staging: wave 0/1 -> A rows 0-63/64-127; wave 2/3 -> B rows 0-63/64-127
    const int half_ = wave & 1;
    const _Float16* src = (wave < 2) ? A : B;
    const int tb = ((wave < 2) ? m0 : n0) + half_ * 64;
    const int sl_st = ((lane >> 2) & 3) ^ ((lane >> 4) & 3);
    const _Float16* p0 = src + (size_t)(tb + (lane >> 2)) * K + (((lane & 3) ^ sl_st) << 3);
    _Float16* ldsw = &lds[(wave >> 1) * 4096 + half_ * 2048];

    const int lr = lane & 15;
    const int lq = lane >> 4;
    const int wm = (wave >> 1) * 64;
    const int wn = (wave & 1) * 64;
    const int sl_rd = (lr & 3) ^ ((lr >> 2) & 3);
    const int slot = ((lq ^ sl_rd) << 3);

    f32x4 acc[4][4];
#pragma unroll
    for (int m = 0; m < 4; ++m)
#pragma unroll
        for (int n = 0; n < 4; ++n) acc[m][n] = (f32x4){0.f, 0.f, 0.f, 0.f};

#pragma unroll
    for (int c = 0; c < 4; ++c)
        GLD16(p0 + (size_t)c * 16 * K, ldsw + c * 512);

    const int NK = K >> 5;
    for (int ks = 0; ks < NK; ++ks) {
        __syncthreads();     // vmcnt drained -> tile ks resident

        f16x8 af[4], bf[4];
#pragma unroll
        for (int m = 0; m < 4; ++m)
            af[m] = *(const f16x8*)&lds[((wm + m * 16 + lr) << 5) + slot];
#pragma unroll
        for (int n = 0; n < 4; ++n)
            bf[n] = *(const f16x8*)&lds[4096 + ((wn + n * 16 + lr) << 5) + slot];
#pragma unroll
        for (int m = 0; m < 4; ++m)
#pragma unroll
            for (int n = 0; n < 4; ++n)
                acc[m][n] = __builtin_amdgcn_mfma_f32_16x16x32_f16(af[m], bf[n], acc[m][n], 0, 0, 0);

        __syncthreads();     // all waves done reading LDS
        if (ks + 1 < NK) {
            const int k0 = (ks + 1) << 5;
#pragma unroll
            for (int c = 0; c < 4; ++c)
                GLD16(p0 + (size_t)c * 16 * K + k0, ldsw + c * 512);
        }
    }

    // C layout: col = lane&15, row = (lane>>4)*4 + j
#pragma unroll
    for (int m = 0; m < 4; ++m) {
        const int row = m0 + wm + m * 16 + lq * 4;
#pragma unroll
        for (int n = 0; n < 4; ++n) {
            const int col = n0 + wn + n * 16 + lr;
#pragma unroll
            for (int j = 0; j < 4; ++j)
                if (row + j < Mstore)
                    C[(size_t)(row + j) * N + col] = acc[m][n][j];
        }
    }
}

// ---------------- RoPE cos/sin tables ----------------
__global__ void rope_table_kernel(const int* __restrict__ pos,
                                  float* __restrict__ cosT, float* __restrict__ sinT)
{
    int s = blockIdx.x;
    int j = threadIdx.x;               // 0..63
    float p = (float)pos[s];
    float expnt = (2.0f * (float)j) * (1.0f / 128.0f);
    float inv_freq = powf(10000.0f, -expnt);
    float f = p * inv_freq;
    cosT[s * 64 + j] = cosf(f);
    sinT[s * 64 + j] = sinf(f);
}

// ---------------- RoPE apply -> fp16 planes for Q and K ----------------
__global__ void rope_f16_kernel(const float* __restrict__ q, const float* __restrict__ k,
                                const float* __restrict__ cosT, const float* __restrict__ sinT,
                                _Float16* __restrict__ qf, _Float16* __restrict__ kf)
{
    int idx = blockIdx.x * 256 + threadIdx.x;
    int s = idx >> 11;
    int rem = idx & 2047;
    int h = rem >> 6;
    int d = rem & 63;
    float c = cosT[s * 64 + d], sn = sinT[s * 64 + d];
    size_t base = (size_t)s * HIDDEN + h * HD + d;
    float a = q[base], b = q[base + 64];
    qf[base]      = (_Float16)(a * c - b * sn);
    qf[base + 64] = (_Float16)(b * c + a * sn);
    a = k[base]; b = k[base + 64];
    kf[base]      = (_Float16)(a * c - b * sn);
    kf[base + 64] = (_Float16)(b * c + a * sn);
}

// ---------------- V [s][h*128+d] fp32 -> Vt fp16 [h][d][s] ----------------
__global__ __launch_bounds__(256) void vtrans_f16_kernel(
    const float* __restrict__ v, _Float16* __restrict__ vt)
{
    __shared__ float Vs[64][129];
    const int h = blockIdx.y;
    const int s0 = blockIdx.x * 64;
    const int tid = threadIdx.x;
#pragma unroll
    for (int i = 0; i < 8; ++i) {
        int flat = tid + 256 * i;          // 0..2047
        int r = flat >> 5;
        int c4 = (flat & 31) * 4;
        float4 t = *(const float4*)(v + (size_t)(s0 + r) * HIDDEN + h * HD + c4);
        Vs[r][c4] = t.x; Vs[r][c4 + 1] = t.y; Vs[r][c4 + 2] = t.z; Vs[r][c4 + 3] = t.w;
    }
    __syncthreads();
#pragma unroll
    for (int pass = 0; pass < 4; ++pass) {
        int d = pass * 32 + (tid >> 3);
        int sb = (tid & 7) * 8;
        f16x8 o;
#pragma unroll
        for (int e = 0; e < 8; ++e) o[e] = (_Float16)Vs[sb + e][d];
        *(f16x8*)(vt + ((size_t)h * HD + d) * SEQQ + s0 + sb) = o;
    }
}

// ---------------- MFMA fp16 flash attention, causal + gated prefix ----------------
// grid (NH, SEQQ/64), 256 threads = 4 waves; wave w owns q-rows q0+w*16..+15.
__global__ __launch_bounds__(256) void attn_f16_kernel(
    const _Float16* __restrict__ Qf, const _Float16* __restrict__ Kf,
    const _Float16* __restrict__ Vtf,
    const float* __restrict__ kp, const float* __restrict__ vp,
    const float* __restrict__ gate, float* __restrict__ out)
{
    __shared__ _Float16 KVs[64 * 128];   // 16KB: K tile [j][128] then Vt tile [d][64]
    __shared__ float Ps[4][16][68];      // P transpose buffer per wave
    __shared__ float Pp[4][16][12];      // gated prefix probs per wave

    const int h = blockIdx.x;
    const int q0 = blockIdx.y * 64;
    const int tid = threadIdx.x;
    const int wave = tid >> 6;
    const int lane = tid & 63;
    const int lr = lane & 15;
    const int lq = lane >> 4;
    const float scale = 0.088388347648318447f;   // 1/sqrt(128)

    // ---- Q fragments (a-frag: row=lr, k=lq*8+e within 32-chunk c) ----
    const int qrow = q0 + wave * 16 + lr;
    f16x8 qh[4];
#pragma unroll
    for (int c = 0; c < 4; ++c)
        qh[c] = *(const f16x8*)(Qf + (size_t)qrow * HIDDEN + h * HD + c * 32 + lq * 8);

    f32x4 accO[8];
#pragma unroll
    for (int n = 0; n < 8; ++n) accO[n] = (f32x4){0.f, 0.f, 0.f, 0.f};
    float m_run[4] = {-INFINITY, -INFINITY, -INFINITY, -INFINITY};
    float l_run[4] = {0.f, 0.f, 0.f, 0.f};

    const int ntiles = blockIdx.y + 1;
    for (int t = 0; t < ntiles; ++t) {
        const int j0 = t * 64;
        __syncthreads();                 // prev tile's PV reads done

        // ---- stage K tile: wave w -> rows 16w..16w+15 (4 chunks of 4 rows) ----
        {
            const int rl = lane >> 4;    // row in chunk 0..3
            const int ch = lane & 15;
#pragma unroll
            for (int ii = 0; ii < 4; ++ii) {
                int r = wave * 16 + ii * 4 + rl;
                int chs = ch ^ (r & 7);
                const _Float16* g = Kf + (size_t)(j0 + r) * HIDDEN + h * HD + chs * 8;
                GLD16(g, &KVs[(wave * 16 + ii * 4) * 128]);
            }
        }
        __syncthreads();                 // K resident

        // ---- S = Q K^T, 16x64 per wave ----
        f32x4 sacc[4];
#pragma unroll
        for (int n = 0; n < 4; ++n) sacc[n] = (f32x4){0.f, 0.f, 0.f, 0.f};
#pragma unroll
        for (int c = 0; c < 4; ++c) {
#pragma unroll
            for (int n = 0; n < 4; ++n) {
                int row = n * 16 + lr;
                int chs = (4 * c + lq) ^ (lr & 7);
                f16x8 kf8 = *(const f16x8*)&KVs[row * 128 + chs * 8];
                sacc[n] = __builtin_amdgcn_mfma_f32_16x16x32_f16(qh[c], kf8, sacc[n], 0, 0, 0);
            }
        }

        // ---- scale + causal mask + online softmax (C rows = lq*4+j) ----
#pragma unroll
        for (int j = 0; j < 4; ++j) {
            const int grow = q0 + wave * 16 + lq * 4 + j;
#pragma unroll
            for (int n = 0; n < 4; ++n) {
                int gcol = j0 + n * 16 + lr;
                float val = sacc[n][j] * scale;
                sacc[n][j] = (gcol > grow) ? -INFINITY : val;
            }
            float mx = fmaxf(fmaxf(sacc[0][j], sacc[1][j]), fmaxf(sacc[2][j], sacc[3][j]));
            mx = fmaxf(mx, __shfl_xor(mx, 1));
            mx = fmaxf(mx, __shfl_xor(mx, 2));
            mx = fmaxf(mx, __shfl_xor(mx, 4));
            mx = fmaxf(mx, __shfl_xor(mx, 8));
            float mn = fmaxf(m_run[j], mx);
            float corr = expf(m_run[j] - mn);   // 0 on first tile
            m_run[j] = mn;
            float ls = 0.f;
#pragma unroll
            for (int n = 0; n < 4; ++n) {
                float p = expf(sacc[n][j] - mn);
                Ps[wave][lq * 4 + j][n * 16 + lr] = p;
                ls += p;
            }
            ls += __shfl_xor(ls, 1);
            ls += __shfl_xor(ls, 2);
            ls += __shfl_xor(ls, 4);
            ls += __shfl_xor(ls, 8);
            l_run[j] = l_run[j] * corr + ls;
#pragma unroll
            for (int n = 0; n < 8; ++n) accO[n][j] *= corr;
        }

        __syncthreads();                 // all waves done reading K LDS

        // ---- stage Vt tile: wave w -> d rows 32w..32w+31 (4 chunks of 8 rows) ----
        {
            const int dl = lane >> 3;    // row in chunk 0..7
            const int vch = lane & 7;
#pragma unroll
            for (int ii = 0; ii < 4; ++ii) {
                int d = wave * 32 + ii * 8 + dl;
                int chs = vch ^ (d & 7);
                const _Float16* g = Vtf + ((size_t)h * HD + d) * SEQQ + j0 + chs * 8;
                GLD16(g, &KVs[(wave * 32 + ii * 8) * 64]);
            }
        }
        __syncthreads();                 // Vt resident

        // ---- PV: out += P V ----
#pragma unroll
        for (int jc = 0; jc < 2; ++jc) {
            float pv[8];
            *(float4*)&pv[0] = *(const float4*)&Ps[wave][lr][jc * 32 + lq * 8];
            *(float4*)&pv[4] = *(const float4*)&Ps[wave][lr][jc * 32 + lq * 8 + 4];
            f16x8 pa;
#pragma unroll
            for (int e = 0; e < 8; ++e) pa[e] = (_Float16)pv[e];
#pragma unroll
            for (int n = 0; n < 8; ++n) {
                int row = n * 16 + lr;
                int chv = (jc * 4 + lq) ^ (lr & 7);
                f16x8 vf = *(const f16x8*)&KVs[row * 64 + chv * 8];
                accO[n] = __builtin_amdgcn_mfma_f32_16x16x32_f16(pa, vf, accO[n], 0, 0, 0);
            }
        }
    }

    // ---- normalize token part ----
#pragma unroll
    for (int j = 0; j < 4; ++j) {
        float inv_l = 1.0f / l_run[j];
#pragma unroll
        for (int n = 0; n < 8; ++n) accO[n][j] *= inv_l;
    }

    // ---- gated prefix (separate softmax over 10 keys, no RoPE) ----
    {
        float g = tanhf(gate[h]);
        float sp[PLEN];
        float mp = -INFINITY;
#pragma unroll
        for (int i = 0; i < PLEN; ++i) {
            const float* kpr = kp + (size_t)i * HIDDEN + h * HD;
            float s = 0.f;
#pragma unroll
            for (int c = 0; c < 4; ++c)
#pragma unroll
                for (int e = 0; e < 8; ++e)
                    s = fmaf((float)qh[c][e], kpr[c * 32 + lq * 8 + e], s);
            s += __shfl_xor(s, 16);
            s += __shfl_xor(s, 32);
            sp[i] = s * scale;
            mp = fmaxf(mp, sp[i]);
        }
        float ssum = 0.f;
#pragma unroll
        for (int i = 0; i < PLEN; ++i) { sp[i] = expf(sp[i] - mp); ssum += sp[i]; }
        float gs = g / ssum;
        if (lq == 0) {
#pragma unroll
            for (int i = 0; i < PLEN; ++i) Pp[wave][lr][i] = sp[i] * gs;
        }
#pragma unroll
        for (int i = 0; i < PLEN; ++i) {
            float vv[8];
#pragma unroll
            for (int n = 0; n < 8; ++n)
                vv[n] = vp[(size_t)i * HIDDEN + h * HD + n * 16 + lr];
#pragma unroll
            for (int j = 0; j < 4; ++j) {
                float w = Pp[wave][lq * 4 + j][i];
#pragma unroll
                for (int n = 0; n < 8; ++n) accO[n][j] = fmaf(w, vv[n], accO[n][j]);
            }
        }
    }

    // ---- store fp32 output ----
#pragma unroll
    for (int n = 0; n < 8; ++n)
#pragma unroll
        for (int j = 0; j < 4; ++j)
            out[(size_t)(q0 + wave * 16 + lq * 4 + j) * HIDDEN + h * HD + n * 16 + lr] = accO[n][j];
}

// ================= fp32 fallback path (ws too small) =================
__global__ __launch_bounds__(256) void gemm_nt_kernel(
    const float* __restrict__ A, const float* __restrict__ B, float* __restrict__ C,
    int M, int N, int K)
{
    __shared__ float As[8][132];
    __shared__ float Bs[8][132];
    const int tid = threadIdx.x;
    const int tx = tid & 15, ty = tid >> 4;
    const int m0 = blockIdx.y * 128, n0 = blockIdx.x * 128;
    const int lr = tid >> 1;
    const int lk = (tid & 1) * 4;
    const bool aval = (m0 + lr) < M;
    const float* Ap = A + (size_t)(m0 + lr) * K + lk;
    const float* Bp = B + (size_t)(n0 + lr) * K + lk;

    float acc[8][8];
#pragma unroll
    for (int i = 0; i < 8; ++i)
#pragma unroll
        for (int j = 0; j < 8; ++j) acc[i][j] = 0.0f;

    for (int k0 = 0; k0 < K; k0 += 8) {
        float4 a4 = make_float4(0.f, 0.f, 0.f, 0.f);
        if (aval) a4 = *(const float4*)(Ap + k0);
        float4 b4 = *(const float4*)(Bp + k0);
        __syncthreads();
        As[lk + 0][lr] = a4.x; As[lk + 1][lr] = a4.y; As[lk + 2][lr] = a4.z; As[lk + 3][lr] = a4.w;
        Bs[lk + 0][lr] = b4.x; Bs[lk + 1][lr] = b4.y; Bs[lk + 2][lr] = b4.z; Bs[lk + 3][lr] = b4.w;
        __syncthreads();
#pragma unroll
        for (int kk = 0; kk < 8; ++kk) {
            float4 a0 = *(const float4*)&As[kk][ty * 8];
            float4 a1 = *(const float4*)&As[kk][ty * 8 + 4];
            float4 b0 = *(const float4*)&Bs[kk][tx * 8];
            float4 b1 = *(const float4*)&Bs[kk][tx * 8 + 4];
            float a[8] = {a0.x, a0.y, a0.z, a0.w, a1.x, a1.y, a1.z, a1.w};
            float b[8] = {b0.x, b0.y, b0.z, b0.w, b1.x, b1.y, b1.z, b1.w};
#pragma unroll
            for (int i = 0; i < 8; ++i)
#pragma unroll
                for (int j = 0; j < 8; ++j)
                    acc[i][j] = fmaf(a[i], b[j], acc[i][j]);
        }
    }
#pragma unroll
    for (int i = 0; i < 8; ++i) {
        int row = m0 + ty * 8 + i;
        if (row < M) {
            float* Cp = C + (size_t)row * N + n0 + tx * 8;
            *(float4*)Cp       = make_float4(acc[i][0], acc[i][1], acc[i][2], acc[i][3]);
            *(float4*)(Cp + 4) = make_float4(acc[i][4], acc[i][5], acc[i][6], acc[i][7]);
        }
    }
}

__global__ void rope_apply_kernel(float* __restrict__ q, float* __restrict__ k,
                                  const float* __restrict__ cosT, const float* __restrict__ sinT)
{
    int idx = blockIdx.x * 256 + threadIdx.x;
    int s = idx >> 11;
    int rem = idx & 2047;
    int h = rem >> 6;
    int d = rem & 63;
    float c = cosT[s * 64 + d], sn = sinT[s * 64 + d];
    size_t base = (size_t)s * HIDDEN + h * HD + d;
    float a = q[base], b = q[base + 64];
    q[base]      = a * c - b * sn;
    q[base + 64] = b * c + a * sn;
    a = k[base]; b = k[base + 64];
    k[base]      = a * c - b * sn;
    k[base + 64] = b * c + a * sn;
}

__global__ __launch_bounds__(256) void attn_kernel(
    const float* __restrict__ q, const float* __restrict__ k, const float* __restrict__ v,
    const float* __restrict__ kp, const float* __restrict__ vp,
    const float* __restrict__ gate, float* __restrict__ out)
{
    __shared__ float Qt[128][36];
    __shared__ float KV[128 * 68];
    __shared__ float Psh[QT][68];

    const int h = blockIdx.y;
    const int r0 = blockIdx.x * QT;
    const int tid = threadIdx.x;
    const int orow = tid >> 3;
    const int oc4 = (tid & 7) * 4;
    const int sy = tid >> 4;
    const int sx = tid & 15;
    const float scale = 0.088388347648318447f;

#pragma unroll
    for (int i = 0; i < 4; ++i) {
        int flat = tid + 256 * i;
        int r = flat >> 5;
        int d = (flat & 31) << 2;
        float4 t = *(const float4*)(q + (size_t)(r0 + r) * HIDDEN + h * HD + d);
        Qt[d + 0][r] = t.x; Qt[d + 1][r] = t.y; Qt[d + 2][r] = t.z; Qt[d + 3][r] = t.w;
    }

    float acc[4][4];
#pragma unroll
    for (int u = 0; u < 4; ++u)
#pragma unroll
        for (int i = 0; i < 4; ++i) acc[u][i] = 0.0f;
    float m_run = -INFINITY, l_run = 0.0f;

    const int jb_max = (r0 + QT - 1) >> 6;
    for (int jb = 0; jb <= jb_max; ++jb) {
        const int j0 = jb * KT;
        __syncthreads();
#pragma unroll
        for (int i = 0; i < 8; ++i) {
            int flat = tid + 256 * i;
            int r = flat >> 5;
            int d = (flat & 31) << 2;
            float4 t = *(const float4*)(k + (size_t)(j0 + r) * HIDDEN + h * HD + d);
            KV[(d + 0) * 68 + r] = t.x; KV[(d + 1) * 68 + r] = t.y;
            KV[(d + 2) * 68 + r] = t.z; KV[(d + 3) * 68 + r] = t.w;
        }
        __syncthreads();
        float s8[2][4] = {{0.f, 0.f, 0.f, 0.f}, {0.f, 0.f, 0.f, 0.f}};
        for (int d = 0; d < 128; ++d) {
            float2 qv = *(const float2*)&Qt[d][sy * 2];
            float4 kv4 = *(const float4*)&KV[d * 68 + sx * 4];
            s8[0][0] = fmaf(qv.x, kv4.x, s8[0][0]);
            s8[0][1] = fmaf(qv.x, kv4.y, s8[0][1]);
            s8[0][2] = fmaf(qv.x, kv4.z, s8[0][2]);
            s8[0][3] = fmaf(qv.x, kv4.w, s8[0][3]);
            s8[1][0] = fmaf(qv.y, kv4.x, s8[1][0]);
            s8[1][1] = fmaf(qv.y, kv4.y, s8[1][1]);
            s8[1][2] = fmaf(qv.y, kv4.z, s8[1][2]);
            s8[1][3] = fmaf(qv.y, kv4.w, s8[1][3]);
        }
#pragma unroll
        for (int i = 0; i < 2; ++i) {
            int gr = r0 + sy * 2 + i;
#pragma unroll
            for (int jj = 0; jj < 4; ++jj) {
                int gj = j0 + sx * 4 + jj;
                float val = s8[i][jj] * scale;
                Psh[sy * 2 + i][sx * 4 + jj] = (gj > gr) ? -INFINITY : val;
            }
        }
        __syncthreads();
        {
            const int c0 = (tid & 7) * 8;
            float sv[8];
            float mx = -INFINITY;
#pragma unroll
            for (int i = 0; i < 8; ++i) { sv[i] = Psh[orow][c0 + i]; mx = fmaxf(mx, sv[i]); }
            mx = fmaxf(mx, __shfl_xor(mx, 1));
            mx = fmaxf(mx, __shfl_xor(mx, 2));
            mx = fmaxf(mx, __shfl_xor(mx, 4));
            float m_new = fmaxf(m_run, mx);
            float corr = expf(m_run - m_new);
            float lsum = 0.f;
#pragma unroll
            for (int i = 0; i < 8; ++i) {
                float p = expf(sv[i] - m_new);
                Psh[orow][c0 + i] = p;
                lsum += p;
            }
            lsum += __shfl_xor(lsum, 1);
            lsum += __shfl_xor(lsum, 2);
            lsum += __shfl_xor(lsum, 4);
            l_run = l_run * corr + lsum;
            m_run = m_new;
#pragma unroll
            for (int u = 0; u < 4; ++u)
#pragma unroll
                for (int i = 0; i < 4; ++i) acc[u][i] *= corr;
        }
        __syncthreads();
#pragma unroll
        for (int i = 0; i < 8; ++i) {
            int flat = tid + 256 * i;
            int r = flat >> 5;
            int d = (flat & 31) << 2;
            float4 t = *(const float4*)(v + (size_t)(j0 + r) * HIDDEN + h * HD + d);
            *(float4*)&KV[r * 136 + d] = t;
        }
        __syncthreads();
        for (int j = 0; j < KT; ++j) {
            float p = Psh[orow][j];
#pragma unroll
            for (int u = 0; u < 4; ++u) {
                float4 vv = *(const float4*)&KV[j * 136 + oc4 + u * 32];
                acc[u][0] = fmaf(p, vv.x, acc[u][0]);
                acc[u][1] = fmaf(p, vv.y, acc[u][1]);
                acc[u][2] = fmaf(p, vv.z, acc[u][2]);
                acc[u][3] = fmaf(p, vv.w, acc[u][3]);
            }
        }
    }

    float inv_l = 1.0f / l_run;
#pragma unroll
    for (int u = 0; u < 4; ++u)
#pragma unroll
        for (int i = 0; i < 4; ++i) acc[u][i] *= inv_l;

    {
        float g = tanhf(gate[h]);
        float sp[PLEN];
        float mp = -INFINITY;
#pragma unroll
        for (int i = 0; i < PLEN; ++i) {
            const float* kpr = kp + (size_t)i * HIDDEN + h * HD;
            float s = 0.f;
            for (int d = 0; d < 128; ++d) s = fmaf(Qt[d][orow], kpr[d], s);
            sp[i] = s * scale;
            mp = fmaxf(mp, sp[i]);
        }
        float ssum = 0.f;
#pragma unroll
        for (int i = 0; i < PLEN; ++i) { sp[i] = expf(sp[i] - mp); ssum += sp[i]; }
        float gs = g / ssum;
#pragma unroll
        for (int i = 0; i < PLEN; ++i) {
            float w = sp[i] * gs;
            const float* vpr = vp + (size_t)i * HIDDEN + h * HD;
#pragma unroll
            for (int u = 0; u < 4; ++u) {
                float4 vv = *(const float4*)(vpr + oc4 + u * 32);
                acc[u][0] = fmaf(w, vv.x, acc[u][0]);
                acc[u][1] = fmaf(w, vv.y, acc[u][1]);
                acc[u][2] = fmaf(w, vv.z, acc[u][2]);
                acc[u][3] = fmaf(w, vv.w, acc[u][3]);
            }
        }
    }

    float* op = out + (size_t)(r0 + orow) * HIDDEN + h * HD;
#pragma unroll
    for (int u = 0; u < 4; ++u)
        *(float4*)(op + oc4 + u * 32) = make_float4(acc[u][0], acc[u][1], acc[u][2], acc[u][3]);
}

extern "C" void kernel_launch(void* const* d_in, const int* in_sizes, int n_in,
                              void* d_out, int out_size, void* d_ws, size_t ws_size,
                              hipStream_t stream)
{
    (void)in_sizes; (void)n_in; (void)out_size;
    const float* hidden  = (const float*)d_in[0];
    const int*   pos     = (const int*)d_in[2];
    const float* Wq      = (const float*)d_in[3];
    const float* Wk      = (const float*)d_in[4];
    const float* Wv      = (const float*)d_in[5];
    const float* Wo      = (const float*)d_in[6];
    const float* adapter = (const float*)d_in[7];
    const float* gate    = (const float*)d_in[8];
    float* out = (float*)d_out;

    float* ws = (float*)d_ws;
    const size_t SH = (size_t)SEQQ * HIDDEN;          // 8,388,608
    const size_t WN = (size_t)HIDDEN * HIDDEN;        // 16,777,216
    const size_t PN = (size_t)128 * HIDDEN;
    float* qb   = ws;
    float* kb   = ws + SH;
    float* vb   = ws + 2 * SH;
    float* kpb  = ws + 3 * SH;
    float* vpb  = kpb + (size_t)PLEN * HIDDEN;
    float* cosT = vpb + (size_t)PLEN * HIDDEN;
    float* sinT = cosT + (size_t)SEQQ * 64;
    _Float16* Hf = (_Float16*)(sinT + (size_t)SEQQ * 64);   // SH halves
    _Float16* Wf = Hf + SH;                                 // WN halves
    _Float16* Pf = Wf + WN;                                 // PN halves
    const size_t need = (size_t)((char*)(Pf + PN) - (char*)d_ws);
    const bool use_f16 = (ws_size >= need);

    // overlays: after QKV GEMMs, Wf region holds Qf+Kf (2*SH == WN); Hf region holds Vtf
    _Float16* Qf  = Wf;
    _Float16* Kff = Wf + SH;
    _Float16* Vtf = Hf;
    _Float16* Of  = Hf;      // attn-out fp16 (after attn consumed Vtf)

    rope_table_kernel<<<SEQQ, 64, 0, stream>>>(pos, cosT, sinT);

    dim3 blk(256);
    dim3 gbig(HIDDEN / 128, SEQQ / 128);      // 32 x 16 = 512 blocks
    dim3 gsm(HIDDEN / 128, 1);                // 32 blocks
    const int nH8 = (int)(SH / 8);
    const int nW8 = (int)(WN / 8);

    if (use_f16) {
        cvt_f16_kernel<<<nH8 / 256, blk, 0, stream>>>(hidden, Hf, nH8);
        cvt_pad_f16_kernel<<<(int)(PN / 8 / 256), blk, 0, stream>>>(adapter, Pf);

        cvt_f16_kernel<<<nW8 / 256, blk, 0, stream>>>(Wq, Wf, nW8);
        gemm_f16_kernel<<<gbig, blk, 0, stream>>>(Hf, Wf, qb, HIDDEN, HIDDEN, SEQQ);

        cvt_f16_kernel<<<nW8 / 256, blk, 0, stream>>>(Wk, Wf, nW8);
        gemm_f16_kernel<<<gbig, blk, 0, stream>>>(Hf, Wf, kb, HIDDEN, HIDDEN, SEQQ);
        gemm_f16_kernel<<<gsm, blk, 0, stream>>>(Pf, Wf, kpb, HIDDEN, HIDDEN, PLEN);

        cvt_f16_kernel<<<nW8 / 256, blk, 0, stream>>>(Wv, Wf, nW8);
        gemm_f16_kernel<<<gbig, blk, 0, stream>>>(Hf, Wf, vb, HIDDEN, HIDDEN, SEQQ);
        gemm_f16_kernel<<<gsm, blk, 0, stream>>>(Pf, Wf, vpb, HIDDEN, HIDDEN, PLEN);

        // Wf dead -> write Qf/Kf; Hf dead -> Vtf
        rope_f16_kernel<<<(SEQQ * 2048) / 256, blk, 0, stream>>>(qb, kb, cosT, sinT, Qf, Kff);
        vtrans_f16_kernel<<<dim3(SEQQ / 64, NH), blk, 0, stream>>>(vb, Vtf);

        attn_f16_kernel<<<dim3(NH, SEQQ / 64), blk, 0, stream>>>(
            Qf, Kff, Vtf, kpb, vpb, gate, qb);

        cvt_f16_kernel<<<nH8 / 256, blk, 0, stream>>>(qb, Of, nH8);
        cvt_f16_kernel<<<nW8 / 256, blk, 0, stream>>>(Wo, Wf, nW8);
        gemm_f16_kernel<<<gbig, blk, 0, stream>>>(Of, Wf, out, HIDDEN, HIDDEN, SEQQ);
    } else {
        gemm_nt_kernel<<<gbig, blk, 0, stream>>>(hidden, Wq, qb, SEQQ, HIDDEN, HIDDEN);
        gemm_nt_kernel<<<gbig, blk, 0, stream>>>(hidden, Wk, kb, SEQQ, HIDDEN, HIDDEN);
        gemm_nt_kernel<<<gbig, blk, 0, stream>>>(hidden, Wv, vb, SEQQ, HIDDEN, HIDDEN);
        gemm_nt_kernel<<<gsm, blk, 0, stream>>>(adapter, Wk, kpb, PLEN, HIDDEN, HIDDEN);
        gemm_nt_kernel<<<gsm, blk, 0, stream>>>(adapter, Wv, vpb, PLEN, HIDDEN, HIDDEN);
        rope_apply_kernel<<<(SEQQ * 2048) / 256, 256, 0, stream>>>(qb, kb, cosT, sinT);
        attn_kernel<<<dim3(SEQQ / QT, NH), blk, 0, stream>>>(qb, kb, vb, kpb, vpb, gate, qb);
        gemm_nt_kernel<<<gbig, blk, 0, stream>>>(qb, Wo, out, SEQQ, HIDDEN, HIDDEN);
    }
}

// Round 8
// 643.751 us; speedup vs baseline: 9.6486x; 1.3714x over previous
//
#include <hip/hip_runtime.h>
#include <math.h>

#define HIDDEN 4096
#define NH 32
#define HD 128
#define PLEN 10
#define SEQQ 2048
#define QT 32
#define KT 64
#define QKVLD 12288

typedef __attribute__((ext_vector_type(8))) _Float16 f16x8;
typedef __attribute__((ext_vector_type(4))) float f32x4;

// async global->LDS, 16 bytes per lane; LDS dest is wave-uniform base + lane*16
#define GLD16(g, l) __builtin_amdgcn_global_load_lds( \
        (const __attribute__((address_space(1))) void*)(g), \
        (__attribute__((address_space(3))) void*)(l), 16, 0, 0)

// ---------------- fp32 -> fp16 plane, 8 elems/thread ----------------
__global__ __launch_bounds__(256) void cvt_f16_kernel(
    const float* __restrict__ x, _Float16* __restrict__ y, int n8)
{
    int idx = blockIdx.x * 256 + threadIdx.x;
    if (idx >= n8) return;
    const float4* xp = (const float4*)x;
    float4 a = xp[idx * 2], b = xp[idx * 2 + 1];
    f16x8 o;
    o[0] = (_Float16)a.x; o[1] = (_Float16)a.y; o[2] = (_Float16)a.z; o[3] = (_Float16)a.w;
    o[4] = (_Float16)b.x; o[5] = (_Float16)b.y; o[6] = (_Float16)b.z; o[7] = (_Float16)b.w;
    *(f16x8*)(y + (size_t)idx * 8) = o;
}

// ---------------- adapter (10x4096) -> zero-padded 128x4096 fp16 ----------------
__global__ __launch_bounds__(256) void cvt_pad_f16_kernel(
    const float* __restrict__ src, _Float16* __restrict__ y)
{
    int idx = blockIdx.x * 256 + threadIdx.x;   // 65536 chunks of 8 elems
    int row = idx >> 9;
    f16x8 o;
    if (row < PLEN) {
        const float4* xp = (const float4*)src;
        float4 a = xp[idx * 2], b = xp[idx * 2 + 1];
        o[0] = (_Float16)a.x; o[1] = (_Float16)a.y; o[2] = (_Float16)a.z; o[3] = (_Float16)a.w;
        o[4] = (_Float16)b.x; o[5] = (_Float16)b.y; o[6] = (_Float16)b.z; o[7] = (_Float16)b.w;
    } else {
#pragma unroll
        for (int i = 0; i < 8; ++i) o[i] = (_Float16)0.0f;
    }
    *(f16x8*)(y + (size_t)idx * 8) = o;
}

// ---------------- fp16 MFMA GEMM NT: C = A * B^T ----------------
// 128x128 tile, BK=64, 256 threads = 4 waves, global_load_lds staging,
// XOR slot swizzle (pre-swizzled global src + swizzled ds_read). Output fp16 or fp32.
template <typename OT>
__global__ __launch_bounds__(256) void gemm_f16_kernel(
    const _Float16* __restrict__ A, const _Float16* __restrict__ B,
    OT* __restrict__ C, int N, int K, int Mstore)
{
    __shared__ _Float16 lds[2 * 8192];   // plane A [128][64], plane B [128][64]

    const int tid = threadIdx.x;
    const int lane = tid & 63;
    const int wave = tid >> 6;

    // XCD-aware bijective swizzle (nwg % 8 == 0 for all our grids)
    const int gx = gridDim.x;
    const int nwg = gx * gridDim.y;
    const int flat = blockIdx.y * gx + blockIdx.x;
    const int cpx = nwg >> 3;
    const int sw = (flat & 7) * cpx + (flat >> 3);
    const int m0 = (sw / gx) * 128;
    const int n0 = (sw % gx) * 128;

    // staging: wave w -> plane w>>1 (A/B), half w&1 (rows 0-63 / 64-127)
    // chunk c (0..7) = 8 rows; lane: row_in_chunk = lane>>3, slot = lane&7 (8 f16)
    const _Float16* srcp = (wave < 2) ? A : B;
    const int tb = ((wave < 2) ? m0 : n0) + (wave & 1) * 64;
    const int swz = ((lane & 7) ^ ((lane >> 3) & 7)) << 3;   // pre-swizzled global col
    const _Float16* p0 = srcp + (size_t)(tb + (lane >> 3)) * K + swz;
    _Float16* ldsw = &lds[(wave >> 1) * 8192 + (wave & 1) * 4096];

    const int lr = lane & 15;
    const int lq = lane >> 4;
    const int wm = (wave >> 1) * 64;
    const int wn = (wave & 1) * 64;

    f32x4 acc[4][4];
#pragma unroll
    for (int m = 0; m < 4; ++m)
#pragma unroll
        for (int n = 0; n < 4; ++n) acc[m][n] = (f32x4){0.f, 0.f, 0.f, 0.f};

#pragma unroll
    for (int c = 0; c < 8; ++c)
        GLD16(p0 + (size_t)c * 8 * K, ldsw + c * 512);

    const int NK = K >> 6;
    for (int ks = 0; ks < NK; ++ks) {
        __syncthreads();     // vmcnt drained -> tile ks resident

#pragma unroll
        for (int kc = 0; kc < 2; ++kc) {
            f16x8 af[4], bf[4];
#pragma unroll
            for (int m = 0; m < 4; ++m) {
                int r = wm + m * 16 + lr;
                af[m] = *(const f16x8*)&lds[(r << 6) + ((((kc << 2) + lq) ^ (lr & 7)) << 3)];
            }
#pragma unroll
            for (int n = 0; n < 4; ++n) {
                int r = wn + n * 16 + lr;
                bf[n] = *(const f16x8*)&lds[8192 + (r << 6) + ((((kc << 2) + lq) ^ (lr & 7)) << 3)];
            }
#pragma unroll
            for (int m = 0; m < 4; ++m)
#pragma unroll
                for (int n = 0; n < 4; ++n)
                    acc[m][n] = __builtin_amdgcn_mfma_f32_16x16x32_f16(af[m], bf[n], acc[m][n], 0, 0, 0);
        }

        __syncthreads();     // all waves done reading LDS
        if (ks + 1 < NK) {
            const int k0 = (ks + 1) << 6;
#pragma unroll
            for (int c = 0; c < 8; ++c)
                GLD16(p0 + (size_t)c * 8 * K + k0, ldsw + c * 512);
        }
    }

    // C layout: col = lane&15, row = (lane>>4)*4 + j
#pragma unroll
    for (int m = 0; m < 4; ++m) {
        const int row = m0 + wm + m * 16 + lq * 4;
#pragma unroll
        for (int n = 0; n < 4; ++n) {
            const int col = n0 + wn + n * 16 + lr;
#pragma unroll
            for (int j = 0; j < 4; ++j)
                if (row + j < Mstore)
                    C[(size_t)(row + j) * N + col] = (OT)acc[m][n][j];
        }
    }
}

// ---------------- RoPE cos/sin tables ----------------
__global__ void rope_table_kernel(const int* __restrict__ pos,
                                  float* __restrict__ cosT, float* __restrict__ sinT)
{
    int s = blockIdx.x;
    int j = threadIdx.x;               // 0..63
    float p = (float)pos[s];
    float expnt = (2.0f * (float)j) * (1.0f / 128.0f);
    float inv_freq = powf(10000.0f, -expnt);
    float f = p * inv_freq;
    cosT[s * 64 + j] = cosf(f);
    sinT[s * 64 + j] = sinf(f);
}

// ---------------- RoPE apply in place on fp16 QKV buffer (q and k parts) ----------------
__global__ void rope_f16ip_kernel(_Float16* __restrict__ qkv,
                                  const float* __restrict__ cosT, const float* __restrict__ sinT)
{
    int idx = blockIdx.x * 256 + threadIdx.x;
    int s = idx >> 11;
    int rem = idx & 2047;
    int h = rem >> 6;
    int d = rem & 63;
    float c = cosT[s * 64 + d], sn = sinT[s * 64 + d];
    size_t base = (size_t)s * QKVLD + h * HD + d;
    float a = (float)qkv[base], b = (float)qkv[base + 64];
    qkv[base]      = (_Float16)(a * c - b * sn);
    qkv[base + 64] = (_Float16)(b * c + a * sn);
    size_t kb = base + HIDDEN;
    a = (float)qkv[kb]; b = (float)qkv[kb + 64];
    qkv[kb]      = (_Float16)(a * c - b * sn);
    qkv[kb + 64] = (_Float16)(b * c + a * sn);
}

// ---------------- V fp16 [s][QKVLD] cols -> Vt fp16 [h][d][s] ----------------
__global__ __launch_bounds__(256) void vtrans_f16_kernel(
    const _Float16* __restrict__ v, _Float16* __restrict__ vt)
{
    __shared__ _Float16 Vs[64][136];
    const int h = blockIdx.y;
    const int s0 = blockIdx.x * 64;
    const int tid = threadIdx.x;
#pragma unroll
    for (int i = 0; i < 4; ++i) {
        int flat = tid + 256 * i;          // 0..1023
        int r = flat >> 4;
        int c8 = (flat & 15) * 8;
        *(f16x8*)&Vs[r][c8] = *(const f16x8*)(v + (size_t)(s0 + r) * QKVLD + h * HD + c8);
    }
    __syncthreads();
#pragma unroll
    for (int pass = 0; pass < 4; ++pass) {
        int d = pass * 32 + (tid >> 3);
        int sb = (tid & 7) * 8;
        f16x8 o;
#pragma unroll
        for (int e = 0; e < 8; ++e) o[e] = Vs[sb + e][d];
        *(f16x8*)(vt + ((size_t)h * HD + d) * SEQQ + s0 + sb) = o;
    }
}

// ---------------- MFMA fp16 flash attention, causal + gated prefix ----------------
// grid (NH, SEQQ/64), 256 threads = 4 waves; wave w owns q-rows q0+w*16..+15.
// Q/K read from QKV fp16 buffer (stride QKVLD); out fp16 stride HIDDEN.
__global__ __launch_bounds__(256) void attn_f16_kernel(
    const _Float16* __restrict__ Qf, const _Float16* __restrict__ Kf,
    const _Float16* __restrict__ Vtf,
    const float* __restrict__ kp, const float* __restrict__ vp,
    const float* __restrict__ gate, _Float16* __restrict__ out)
{
    __shared__ _Float16 KVs[64 * 128];   // 16KB: K tile [j][128] then Vt tile [d][64]
    __shared__ float Ps[4][16][68];      // P transpose buffer per wave
    __shared__ float Pp[4][16][12];      // gated prefix probs per wave

    const int h = blockIdx.x;
    const int q0 = blockIdx.y * 64;
    const int tid = threadIdx.x;
    const int wave = tid >> 6;
    const int lane = tid & 63;
    const int lr = lane & 15;
    const int lq = lane >> 4;
    const float scale = 0.088388347648318447f;                 // 1/sqrt(128)
    const float scale2 = 0.088388347648318447f * 1.4426950408889634f;  // *log2(e)

    // ---- Q fragments (a-frag: row=lr, k=lq*8+e within 32-chunk c) ----
    const int qrow = q0 + wave * 16 + lr;
    f16x8 qh[4];
#pragma unroll
    for (int c = 0; c < 4; ++c)
        qh[c] = *(const f16x8*)(Qf + (size_t)qrow * QKVLD + h * HD + c * 32 + lq * 8);

    f32x4 accO[8];
#pragma unroll
    for (int n = 0; n < 8; ++n) accO[n] = (f32x4){0.f, 0.f, 0.f, 0.f};
    float m_run[4] = {-INFINITY, -INFINITY, -INFINITY, -INFINITY};
    float l_run[4] = {0.f, 0.f, 0.f, 0.f};

    const int ntiles = blockIdx.y + 1;
    for (int t = 0; t < ntiles; ++t) {
        const int j0 = t * 64;
        __syncthreads();                 // prev tile's PV reads done

        // ---- stage K tile: wave w -> rows 16w..16w+15 (4 chunks of 4 rows) ----
        {
            const int rl = lane >> 4;    // row in chunk 0..3
            const int ch = lane & 15;
#pragma unroll
            for (int ii = 0; ii < 4; ++ii) {
                int r = wave * 16 + ii * 4 + rl;
                int chs = ch ^ (r & 7);
                const _Float16* g = Kf + (size_t)(j0 + r) * QKVLD + h * HD + chs * 8;
                GLD16(g, &KVs[(wave * 16 + ii * 4) * 128]);
            }
        }
        __syncthreads();                 // K resident

        // ---- S = Q K^T (exp2 domain), 16x64 per wave ----
        f32x4 sacc[4];
#pragma unroll
        for (int n = 0; n < 4; ++n) sacc[n] = (f32x4){0.f, 0.f, 0.f, 0.f};
#pragma unroll
        for (int c = 0; c < 4; ++c) {
#pragma unroll
            for (int n = 0; n < 4; ++n) {
                int row = n * 16 + lr;
                int chs = (4 * c + lq) ^ (lr & 7);
                f16x8 kf8 = *(const f16x8*)&KVs[row * 128 + chs * 8];
                sacc[n] = __builtin_amdgcn_mfma_f32_16x16x32_f16(qh[c], kf8, sacc[n], 0, 0, 0);
            }
        }

        // ---- scale2 + causal mask + online softmax with exp2 ----
#pragma unroll
        for (int j = 0; j < 4; ++j) {
            const int grow = q0 + wave * 16 + lq * 4 + j;
#pragma unroll
            for (int n = 0; n < 4; ++n) {
                int gcol = j0 + n * 16 + lr;
                float val = sacc[n][j] * scale2;
                sacc[n][j] = (gcol > grow) ? -INFINITY : val;
            }
            float mx = fmaxf(fmaxf(sacc[0][j], sacc[1][j]), fmaxf(sacc[2][j], sacc[3][j]));
            mx = fmaxf(mx, __shfl_xor(mx, 1));
            mx = fmaxf(mx, __shfl_xor(mx, 2));
            mx = fmaxf(mx, __shfl_xor(mx, 4));
            mx = fmaxf(mx, __shfl_xor(mx, 8));
            float mn = fmaxf(m_run[j], mx);
            float corr = exp2f(m_run[j] - mn);   // 0 on first tile
            m_run[j] = mn;
            float ls = 0.f;
#pragma unroll
            for (int n = 0; n < 4; ++n) {
                float p = exp2f(sacc[n][j] - mn);
                Ps[wave][lq * 4 + j][n * 16 + lr] = p;
                ls += p;
            }
            ls += __shfl_xor(ls, 1);
            ls += __shfl_xor(ls, 2);
            ls += __shfl_xor(ls, 4);
            ls += __shfl_xor(ls, 8);
            l_run[j] = l_run[j] * corr + ls;
#pragma unroll
            for (int n = 0; n < 8; ++n) accO[n][j] *= corr;
        }

        __syncthreads();                 // all waves done reading K LDS

        // ---- stage Vt tile: wave w -> d rows 32w..32w+31 (4 chunks of 8 rows) ----
        {
            const int dl = lane >> 3;    // row in chunk 0..7
            const int vch = lane & 7;
#pragma unroll
            for (int ii = 0; ii < 4; ++ii) {
                int d = wave * 32 + ii * 8 + dl;
                int chs = vch ^ (d & 7);
                const _Float16* g = Vtf + ((size_t)h * HD + d) * SEQQ + j0 + chs * 8;
                GLD16(g, &KVs[(wave * 32 + ii * 8) * 64]);
            }
        }
        __syncthreads();                 // Vt resident

        // ---- PV: out += P V ----
#pragma unroll
        for (int jc = 0; jc < 2; ++jc) {
            float pv[8];
            *(float4*)&pv[0] = *(const float4*)&Ps[wave][lr][jc * 32 + lq * 8];
            *(float4*)&pv[4] = *(const float4*)&Ps[wave][lr][jc * 32 + lq * 8 + 4];
            f16x8 pa;
#pragma unroll
            for (int e = 0; e < 8; ++e) pa[e] = (_Float16)pv[e];
#pragma unroll
            for (int n = 0; n < 8; ++n) {
                int row = n * 16 + lr;
                int chv = (jc * 4 + lq) ^ (lr & 7);
                f16x8 vf = *(const f16x8*)&KVs[row * 64 + chv * 8];
                accO[n] = __builtin_amdgcn_mfma_f32_16x16x32_f16(pa, vf, accO[n], 0, 0, 0);
            }
        }
    }

    // ---- normalize token part ----
#pragma unroll
    for (int j = 0; j < 4; ++j) {
        float inv_l = 1.0f / l_run[j];
#pragma unroll
        for (int n = 0; n < 8; ++n) accO[n][j] *= inv_l;
    }

    // ---- gated prefix (separate softmax over 10 keys, no RoPE) ----
    {
        float g = tanhf(gate[h]);
        float sp[PLEN];
        float mp = -INFINITY;
#pragma unroll
        for (int i = 0; i < PLEN; ++i) {
            const float* kpr = kp + (size_t)i * QKVLD + h * HD;
            float s = 0.f;
#pragma unroll
            for (int c = 0; c < 4; ++c)
#pragma unroll
                for (int e = 0; e < 8; ++e)
                    s = fmaf((float)qh[c][e], kpr[c * 32 + lq * 8 + e], s);
            s += __shfl_xor(s, 16);
            s += __shfl_xor(s, 32);
            sp[i] = s * scale;
            mp = fmaxf(mp, sp[i]);
        }
        float ssum = 0.f;
#pragma unroll
        for (int i = 0; i < PLEN; ++i) { sp[i] = expf(sp[i] - mp); ssum += sp[i]; }
        float gs = g / ssum;
        if (lq == 0) {
#pragma unroll
            for (int i = 0; i < PLEN; ++i) Pp[wave][lr][i] = sp[i] * gs;
        }
#pragma unroll
        for (int i = 0; i < PLEN; ++i) {
            float vv[8];
#pragma unroll
            for (int n = 0; n < 8; ++n)
                vv[n] = vp[(size_t)i * QKVLD + h * HD + n * 16 + lr];
#pragma unroll
            for (int j = 0; j < 4; ++j) {
                float w = Pp[wave][lq * 4 + j][i];
#pragma unroll
                for (int n = 0; n < 8; ++n) accO[n][j] = fmaf(w, vv[n], accO[n][j]);
            }
        }
    }

    // ---- store fp16 output ----
#pragma unroll
    for (int n = 0; n < 8; ++n)
#pragma unroll
        for (int j = 0; j < 4; ++j)
            out[(size_t)(q0 + wave * 16 + lq * 4 + j) * HIDDEN + h * HD + n * 16 + lr] =
                (_Float16)accO[n][j];
}

// ================= fp32 fallback path (ws too small) =================
__global__ __launch_bounds__(256) void gemm_nt_kernel(
    const float* __restrict__ A, const float* __restrict__ B, float* __restrict__ C,
    int M, int N, int K)
{
    __shared__ float As[8][132];
    __shared__ float Bs[8][132];
    const int tid = threadIdx.x;
    const int tx = tid & 15, ty = tid >> 4;
    const int m0 = blockIdx.y * 128, n0 = blockIdx.x * 128;
    const int lr = tid >> 1;
    const int lk = (tid & 1) * 4;
    const bool aval = (m0 + lr) < M;
    const float* Ap = A + (size_t)(m0 + lr) * K + lk;
    const float* Bp = B + (size_t)(n0 + lr) * K + lk;

    float acc[8][8];
#pragma unroll
    for (int i = 0; i < 8; ++i)
#pragma unroll
        for (int j = 0; j < 8; ++j) acc[i][j] = 0.0f;

    for (int k0 = 0; k0 < K; k0 += 8) {
        float4 a4 = make_float4(0.f, 0.f, 0.f, 0.f);
        if (aval) a4 = *(const float4*)(Ap + k0);
        float4 b4 = *(const float4*)(Bp + k0);
        __syncthreads();
        As[lk + 0][lr] = a4.x; As[lk + 1][lr] = a4.y; As[lk + 2][lr] = a4.z; As[lk + 3][lr] = a4.w;
        Bs[lk + 0][lr] = b4.x; Bs[lk + 1][lr] = b4.y; Bs[lk + 2][lr] = b4.z; Bs[lk + 3][lr] = b4.w;
        __syncthreads();
#pragma unroll
        for (int kk = 0; kk < 8; ++kk) {
            float4 a0 = *(const float4*)&As[kk][ty * 8];
            float4 a1 = *(const float4*)&As[kk][ty * 8 + 4];
            float4 b0 = *(const float4*)&Bs[kk][tx * 8];
            float4 b1 = *(const float4*)&Bs[kk][tx * 8 + 4];
            float a[8] = {a0.x, a0.y, a0.z, a0.w, a1.x, a1.y, a1.z, a1.w};
            float b[8] = {b0.x, b0.y, b0.z, b0.w, b1.x, b1.y, b1.z, b1.w};
#pragma unroll
            for (int i = 0; i < 8; ++i)
#pragma unroll
                for (int j = 0; j < 8; ++j)
                    acc[i][j] = fmaf(a[i], b[j], acc[i][j]);
        }
    }
#pragma unroll
    for (int i = 0; i < 8; ++i) {
        int row = m0 + ty * 8 + i;
        if (row < M) {
            float* Cp = C + (size_t)row * N + n0 + tx * 8;
            *(float4*)Cp       = make_float4(acc[i][0], acc[i][1], acc[i][2], acc[i][3]);
            *(float4*)(Cp + 4) = make_float4(acc[i][4], acc[i][5], acc[i][6], acc[i][7]);
        }
    }
}

__global__ void rope_apply_kernel(float* __restrict__ q, float* __restrict__ k,
                                  const float* __restrict__ cosT, const float* __restrict__ sinT)
{
    int idx = blockIdx.x * 256 + threadIdx.x;
    int s = idx >> 11;
    int rem = idx & 2047;
    int h = rem >> 6;
    int d = rem & 63;
    float c = cosT[s * 64 + d], sn = sinT[s * 64 + d];
    size_t base = (size_t)s * HIDDEN + h * HD + d;
    float a = q[base], b = q[base + 64];
    q[base]      = a * c - b * sn;
    q[base + 64] = b * c + a * sn;
    a = k[base]; b = k[base + 64];
    k[base]      = a * c - b * sn;
    k[base + 64] = b * c + a * sn;
}

__global__ __launch_bounds__(256) void attn_kernel(
    const float* __restrict__ q, const float* __restrict__ k, const float* __restrict__ v,
    const float* __restrict__ kp, const float* __restrict__ vp,
    const float* __restrict__ gate, float* __restrict__ out)
{
    __shared__ float Qt[128][36];
    __shared__ float KV[128 * 68];
    __shared__ float Psh[QT][68];

    const int h = blockIdx.y;
    const int r0 = blockIdx.x * QT;
    const int tid = threadIdx.x;
    const int orow = tid >> 3;
    const int oc4 = (tid & 7) * 4;
    const int sy = tid >> 4;
    const int sx = tid & 15;
    const float scale = 0.088388347648318447f;

#pragma unroll
    for (int i = 0; i < 4; ++i) {
        int flat = tid + 256 * i;
        int r = flat >> 5;
        int d = (flat & 31) << 2;
        float4 t = *(const float4*)(q + (size_t)(r0 + r) * HIDDEN + h * HD + d);
        Qt[d + 0][r] = t.x; Qt[d + 1][r] = t.y; Qt[d + 2][r] = t.z; Qt[d + 3][r] = t.w;
    }

    float acc[4][4];
#pragma unroll
    for (int u = 0; u < 4; ++u)
#pragma unroll
        for (int i = 0; i < 4; ++i) acc[u][i] = 0.0f;
    float m_run = -INFINITY, l_run = 0.0f;

    const int jb_max = (r0 + QT - 1) >> 6;
    for (int jb = 0; jb <= jb_max; ++jb) {
        const int j0 = jb * KT;
        __syncthreads();
#pragma unroll
        for (int i = 0; i < 8; ++i) {
            int flat = tid + 256 * i;
            int r = flat >> 5;
            int d = (flat & 31) << 2;
            float4 t = *(const float4*)(k + (size_t)(j0 + r) * HIDDEN + h * HD + d);
            KV[(d + 0) * 68 + r] = t.x; KV[(d + 1) * 68 + r] = t.y;
            KV[(d + 2) * 68 + r] = t.z; KV[(d + 3) * 68 + r] = t.w;
        }
        __syncthreads();
        float s8[2][4] = {{0.f, 0.f, 0.f, 0.f}, {0.f, 0.f, 0.f, 0.f}};
        for (int d = 0; d < 128; ++d) {
            float2 qv = *(const float2*)&Qt[d][sy * 2];
            float4 kv4 = *(const float4*)&KV[d * 68 + sx * 4];
            s8[0][0] = fmaf(qv.x, kv4.x, s8[0][0]);
            s8[0][1] = fmaf(qv.x, kv4.y, s8[0][1]);
            s8[0][2] = fmaf(qv.x, kv4.z, s8[0][2]);
            s8[0][3] = fmaf(qv.x, kv4.w, s8[0][3]);
            s8[1][0] = fmaf(qv.y, kv4.x, s8[1][0]);
            s8[1][1] = fmaf(qv.y, kv4.y, s8[1][1]);
            s8[1][2] = fmaf(qv.y, kv4.z, s8[1][2]);
            s8[1][3] = fmaf(qv.y, kv4.w, s8[1][3]);
        }
#pragma unroll
        for (int i = 0; i < 2; ++i) {
            int gr = r0 + sy * 2 + i;
#pragma unroll
            for (int jj = 0; jj < 4; ++jj) {
                int gj = j0 + sx * 4 + jj;
                float val = s8[i][jj] * scale;
                Psh[sy * 2 + i][sx * 4 + jj] = (gj > gr) ? -INFINITY : val;
            }
        }
        __syncthreads();
        {
            const int c0 = (tid & 7) * 8;
            float sv[8];
            float mx = -INFINITY;
#pragma unroll
            for (int i = 0; i < 8; ++i) { sv[i] = Psh[orow][c0 + i]; mx = fmaxf(mx, sv[i]); }
            mx = fmaxf(mx, __shfl_xor(mx, 1));
            mx = fmaxf(mx, __shfl_xor(mx, 2));
            mx = fmaxf(mx, __shfl_xor(mx, 4));
            float m_new = fmaxf(m_run, mx);
            float corr = expf(m_run - m_new);
            float lsum = 0.f;
#pragma unroll
            for (int i = 0; i < 8; ++i) {
                float p = expf(sv[i] - m_new);
                Psh[orow][c0 + i] = p;
                lsum += p;
            }
            lsum += __shfl_xor(lsum, 1);
            lsum += __shfl_xor(lsum, 2);
            lsum += __shfl_xor(lsum, 4);
            l_run = l_run * corr + lsum;
            m_run = m_new;
#pragma unroll
            for (int u = 0; u < 4; ++u)
#pragma unroll
                for (int i = 0; i < 4; ++i) acc[u][i] *= corr;
        }
        __syncthreads();
#pragma unroll
        for (int i = 0; i < 8; ++i) {
            int flat = tid + 256 * i;
            int r = flat >> 5;
            int d = (flat & 31) << 2;
            float4 t = *(const float4*)(v + (size_t)(j0 + r) * HIDDEN + h * HD + d);
            *(float4*)&KV[r * 136 + d] = t;
        }
        __syncthreads();
        for (int j = 0; j < KT; ++j) {
            float p = Psh[orow][j];
#pragma unroll
            for (int u = 0; u < 4; ++u) {
                float4 vv = *(const float4*)&KV[j * 136 + oc4 + u * 32];
                acc[u][0] = fmaf(p, vv.x, acc[u][0]);
                acc[u][1] = fmaf(p, vv.y, acc[u][1]);
                acc[u][2] = fmaf(p, vv.z, acc[u][2]);
                acc[u][3] = fmaf(p, vv.w, acc[u][3]);
            }
        }
    }

    float inv_l = 1.0f / l_run;
#pragma unroll
    for (int u = 0; u < 4; ++u)
#pragma unroll
        for (int i = 0; i < 4; ++i) acc[u][i] *= inv_l;

    {
        float g = tanhf(gate[h]);
        float sp[PLEN];
        float mp = -INFINITY;
#pragma unroll
        for (int i = 0; i < PLEN; ++i) {
            const float* kpr = kp + (size_t)i * HIDDEN + h * HD;
            float s = 0.f;
            for (int d = 0; d < 128; ++d) s = fmaf(Qt[d][orow], kpr[d], s);
            sp[i] = s * scale;
            mp = fmaxf(mp, sp[i]);
        }
        float ssum = 0.f;
#pragma unroll
        for (int i = 0; i < PLEN; ++i) { sp[i] = expf(sp[i] - mp); ssum += sp[i]; }
        float gs = g / ssum;
#pragma unroll
        for (int i = 0; i < PLEN; ++i) {
            float w = sp[i] * gs;
            const float* vpr = vp + (size_t)i * HIDDEN + h * HD;
#pragma unroll
            for (int u = 0; u < 4; ++u) {
                float4 vv = *(const float4*)(vpr + oc4 + u * 32);
                acc[u][0] = fmaf(w, vv.x, acc[u][0]);
                acc[u][1] = fmaf(w, vv.y, acc[u][1]);
                acc[u][2] = fmaf(w, vv.z, acc[u][2]);
                acc[u][3] = fmaf(w, vv.w, acc[u][3]);
            }
        }
    }

    float* op = out + (size_t)(r0 + orow) * HIDDEN + h * HD;
#pragma unroll
    for (int u = 0; u < 4; ++u)
        *(float4*)(op + oc4 + u * 32) = make_float4(acc[u][0], acc[u][1], acc[u][2], acc[u][3]);
}

extern "C" void kernel_launch(void* const* d_in, const int* in_sizes, int n_in,
                              void* d_out, int out_size, void* d_ws, size_t ws_size,
                              hipStream_t stream)
{
    (void)in_sizes; (void)n_in; (void)out_size;
    const float* hidden  = (const float*)d_in[0];
    const int*   pos     = (const int*)d_in[2];
    const float* Wq      = (const float*)d_in[3];
    const float* Wk      = (const float*)d_in[4];
    const float* Wv      = (const float*)d_in[5];
    const float* Wo      = (const float*)d_in[6];
    const float* adapter = (const float*)d_in[7];
    const float* gate    = (const float*)d_in[8];
    float* out = (float*)d_out;

    const size_t SH = (size_t)SEQQ * HIDDEN;          // 8,388,608
    const size_t WN = (size_t)HIDDEN * HIDDEN;        // 16,777,216
    const size_t PN = (size_t)128 * HIDDEN;           // 524,288

    // ---- fp16 path layout ----
    float* cosT = (float*)d_ws;
    float* sinT = cosT + (size_t)SEQQ * 64;
    float* AP   = sinT + (size_t)SEQQ * 64;           // adapter proj fp32 [128][12288]
    _Float16* Hf    = (_Float16*)(AP + (size_t)128 * QKVLD);
    _Float16* Wqkvf = Hf + SH;                        // 3*WN
    _Float16* Pf    = Wqkvf + 3 * WN;                 // PN
    _Float16* QKVf  = Pf + PN;                        // 3*SH
    _Float16* Vtf   = QKVf + 3 * SH;                  // SH
    const size_t need = (size_t)((char*)(Vtf + SH) - (char*)d_ws);
    const bool use_f16 = (ws_size >= need);

    _Float16* Of  = Hf;                               // attn out overlays Hf (dead)
    _Float16* Wof = Wqkvf;                            // Wo fp16 overlays Wqkvf (dead)

    rope_table_kernel<<<SEQQ, 64, 0, stream>>>(pos, cosT, sinT);

    dim3 blk(256);
    const int nH8 = (int)(SH / 8);
    const int nW8 = (int)(WN / 8);

    if (use_f16) {
        cvt_f16_kernel<<<nH8 / 256, blk, 0, stream>>>(hidden, Hf, nH8);
        cvt_f16_kernel<<<nW8 / 256, blk, 0, stream>>>(Wq, Wqkvf, nW8);
        cvt_f16_kernel<<<nW8 / 256, blk, 0, stream>>>(Wk, Wqkvf + WN, nW8);
        cvt_f16_kernel<<<nW8 / 256, blk, 0, stream>>>(Wv, Wqkvf + 2 * WN, nW8);
        cvt_pad_f16_kernel<<<(int)(PN / 8 / 256), blk, 0, stream>>>(adapter, Pf);

        // merged QKV projection: [2048][4096] x [12288][4096]^T -> fp16 [2048][12288]
        gemm_f16_kernel<_Float16><<<dim3(QKVLD / 128, SEQQ / 128), blk, 0, stream>>>(
            Hf, Wqkvf, QKVf, QKVLD, HIDDEN, SEQQ);
        // adapter projection (rows 0..9 valid): fp32 [128][12288]
        gemm_f16_kernel<float><<<dim3(QKVLD / 128, 1), blk, 0, stream>>>(
            Pf, Wqkvf, AP, QKVLD, HIDDEN, PLEN);

        rope_f16ip_kernel<<<(SEQQ * 2048) / 256, blk, 0, stream>>>(QKVf, cosT, sinT);
        vtrans_f16_kernel<<<dim3(SEQQ / 64, NH), blk, 0, stream>>>(QKVf + 2 * HIDDEN, Vtf);

        attn_f16_kernel<<<dim3(NH, SEQQ / 64), blk, 0, stream>>>(
            QKVf, QKVf + HIDDEN, Vtf, AP + HIDDEN, AP + 2 * HIDDEN, gate, Of);

        cvt_f16_kernel<<<nW8 / 256, blk, 0, stream>>>(Wo, Wof, nW8);
        gemm_f16_kernel<float><<<dim3(HIDDEN / 128, SEQQ / 128), blk, 0, stream>>>(
            Of, Wof, out, HIDDEN, HIDDEN, SEQQ);
    } else {
        // fp32 fallback (own layout; ws proven >= this)
        float* ws = (float*)d_ws;
        float* qb   = ws;
        float* kb   = ws + SH;
        float* vb   = ws + 2 * SH;
        float* kpb  = ws + 3 * SH;
        float* vpb  = kpb + (size_t)PLEN * HIDDEN;
        float* cT   = vpb + (size_t)PLEN * HIDDEN;
        float* sT   = cT + (size_t)SEQQ * 64;
        rope_table_kernel<<<SEQQ, 64, 0, stream>>>(pos, cT, sT);
        dim3 gbig(HIDDEN / 128, SEQQ / 128);
        dim3 gsm(HIDDEN / 128, 1);
        gemm_nt_kernel<<<gbig, blk, 0, stream>>>(hidden, Wq, qb, SEQQ, HIDDEN, HIDDEN);
        gemm_nt_kernel<<<gbig, blk, 0, stream>>>(hidden, Wk, kb, SEQQ, HIDDEN, HIDDEN);
        gemm_nt_kernel<<<gbig, blk, 0, stream>>>(hidden, Wv, vb, SEQQ, HIDDEN, HIDDEN);
        gemm_nt_kernel<<<gsm, blk, 0, stream>>>(adapter, Wk, kpb, PLEN, HIDDEN, HIDDEN);
        gemm_nt_kernel<<<gsm, blk, 0, stream>>>(adapter, Wv, vpb, PLEN, HIDDEN, HIDDEN);
        rope_apply_kernel<<<(SEQQ * 2048) / 256, 256, 0, stream>>>(qb, kb, cT, sT);
        attn_kernel<<<dim3(SEQQ / QT, NH), blk, 0, stream>>>(qb, kb, vb, kpb, vpb, gate, qb);
        gemm_nt_kernel<<<gbig, blk, 0, stream>>>(qb, Wo, out, SEQQ, HIDDEN, HIDDEN);
    }
}